// Round 1
// baseline (3997.185 us; speedup 1.0000x reference)
//
#include <hip/hip_runtime.h>
#include <math.h>

#define WDIM   512
#define TLEN   512
#define NBATCH 8
#define NHEADS 4
#define DHEAD  128
#define VOCAB  32000
#define NLAY   2
#define FFDIM  2048
#define DFEAT  1024
#define NT     (NBATCH * TLEN)   // 4096 rows

// ---------------- embed + positional encoding ----------------
__global__ __launch_bounds__(128)
void embed_kernel(const int* __restrict__ captions, const float* __restrict__ emb,
                  const float* __restrict__ pe, float* __restrict__ x)
{
    int r = blockIdx.x;            // 0..NT-1
    int t = r % TLEN;
    int cap = captions[r];
    const float4* e4 = (const float4*)(emb + (long)cap * WDIM);
    const float4* p4 = (const float4*)(pe + (long)t * WDIM);
    float4* x4 = (float4*)(x + (long)r * WDIM);
    float4 a = e4[threadIdx.x], b = p4[threadIdx.x];
    x4[threadIdx.x] = make_float4(a.x + b.x, a.y + b.y, a.z + b.z, a.w + b.w);
}

// ---------------- tiled f32 GEMM ----------------
// C[z] = act(alpha * A[z] @ opB(B[z]) + bias)
// batch z decomposed as (zn, zh) = (z/HH, z%HH) with separate strides, so
// per-(batch,head) attention GEMMs map onto one kernel.
// Assumes N, K multiples of tile dims (true for all call sites); M may be ragged (M=8).
#define BM 128
#define BN 128
#define BK 16

template<int TRANSB, int RELU>
__global__ __launch_bounds__(256)
void gemm_kernel(const float* __restrict__ A, int lda, long sAn, long sAh,
                 const float* __restrict__ B, int ldb, long sBn, long sBh,
                 float* __restrict__ C, int ldc, long sCn, long sCh,
                 const float* __restrict__ bias,
                 int M, int N, int K, int HH, float alpha)
{
    int z = blockIdx.z;
    int zn = z / HH, zh = z - zn * HH;
    A += (long)zn * sAn + (long)zh * sAh;
    B += (long)zn * sBn + (long)zh * sBh;
    C += (long)zn * sCn + (long)zh * sCh;
    int bm = blockIdx.y * BM, bn = blockIdx.x * BN;

    __shared__ float As[BK][BM + 4];
    __shared__ float Bs[BK][BN + 4];

    int tid = threadIdx.x;
    int tm = (tid >> 4) << 3;   // 0..120 step 8
    int tn = (tid & 15) << 3;

    float acc[8][8] = {};

    for (int k0 = 0; k0 < K; k0 += BK) {
        // A tile: BM rows x BK k, float4 per thread x2
        {
            int row = tid >> 2;
            int kk  = (tid & 3) << 2;
            #pragma unroll
            for (int rep = 0; rep < 2; rep++) {
                int rr = row + rep * 64;
                float4 val = make_float4(0.f, 0.f, 0.f, 0.f);
                if (bm + rr < M)
                    val = *(const float4*)(A + (long)(bm + rr) * lda + k0 + kk);
                As[kk + 0][rr] = val.x;
                As[kk + 1][rr] = val.y;
                As[kk + 2][rr] = val.z;
                As[kk + 3][rr] = val.w;
            }
        }
        if (TRANSB) {
            // B is (N,K): Bs[k][n] = B[bn+n][k0+k]
            int row = tid >> 2;
            int kk  = (tid & 3) << 2;
            #pragma unroll
            for (int rep = 0; rep < 2; rep++) {
                int nn = row + rep * 64;
                float4 val = *(const float4*)(B + (long)(bn + nn) * ldb + k0 + kk);
                Bs[kk + 0][nn] = val.x;
                Bs[kk + 1][nn] = val.y;
                Bs[kk + 2][nn] = val.z;
                Bs[kk + 3][nn] = val.w;
            }
        } else {
            // B is (K,N): Bs[k][n] = B[k0+k][bn+n]
            int kk = tid >> 5;         // 0..7
            int nn = (tid & 31) << 2;  // 0..124
            #pragma unroll
            for (int rep = 0; rep < 2; rep++) {
                int kr = kk + rep * 8;
                float4 val = *(const float4*)(B + (long)(k0 + kr) * ldb + bn + nn);
                Bs[kr][nn + 0] = val.x;
                Bs[kr][nn + 1] = val.y;
                Bs[kr][nn + 2] = val.z;
                Bs[kr][nn + 3] = val.w;
            }
        }
        __syncthreads();
        #pragma unroll
        for (int kk2 = 0; kk2 < BK; kk2++) {
            float av[8], bv[8];
            *(float4*)&av[0] = *(const float4*)&As[kk2][tm];
            *(float4*)&av[4] = *(const float4*)&As[kk2][tm + 4];
            *(float4*)&bv[0] = *(const float4*)&Bs[kk2][tn];
            *(float4*)&bv[4] = *(const float4*)&Bs[kk2][tn + 4];
            #pragma unroll
            for (int i = 0; i < 8; i++)
                #pragma unroll
                for (int j = 0; j < 8; j++)
                    acc[i][j] = fmaf(av[i], bv[j], acc[i][j]);
        }
        __syncthreads();
    }

    #pragma unroll
    for (int i = 0; i < 8; i++) {
        int gr = bm + tm + i;
        if (gr < M) {
            float outv[8];
            #pragma unroll
            for (int j = 0; j < 8; j++) {
                float vv = acc[i][j] * alpha;
                if (bias) vv += bias[bn + tn + j];
                if (RELU) vv = fmaxf(vv, 0.f);
                outv[j] = vv;
            }
            *(float4*)(C + (long)gr * ldc + bn + tn)     = *(float4*)&outv[0];
            *(float4*)(C + (long)gr * ldc + bn + tn + 4) = *(float4*)&outv[4];
        }
    }
}

// ---------------- causal softmax over rows of (N,H,T,T) ----------------
__global__ __launch_bounds__(256)
void softmax_causal_kernel(float* __restrict__ scores)
{
    long row = blockIdx.x;                 // n*H*T + h*T + s
    int s = (int)(row % TLEN);
    float* p = scores + row * TLEN;
    int tid = threadIdx.x;
    float v0 = p[tid], v1 = p[tid + 256];
    bool m0 = (tid <= s), m1 = (tid + 256 <= s);
    __shared__ float red[256];
    float mx = fmaxf(m0 ? v0 : -INFINITY, m1 ? v1 : -INFINITY);
    red[tid] = mx; __syncthreads();
    for (int off = 128; off > 0; off >>= 1) {
        if (tid < off) red[tid] = fmaxf(red[tid], red[tid + off]);
        __syncthreads();
    }
    mx = red[0]; __syncthreads();
    float e0 = m0 ? expf(v0 - mx) : 0.f;
    float e1 = m1 ? expf(v1 - mx) : 0.f;
    red[tid] = e0 + e1; __syncthreads();
    for (int off = 128; off > 0; off >>= 1) {
        if (tid < off) red[tid] += red[tid + off];
        __syncthreads();
    }
    float inv = 1.f / red[0];
    p[tid]       = e0 * inv;
    p[tid + 256] = e1 * inv;
}

// ---------------- x = LayerNorm(x + t2) ----------------
// t2div = 1: t2 per-row; t2div = TLEN: t2 broadcast per batch (cross-attn path)
__global__ __launch_bounds__(256)
void add_ln_kernel(float* __restrict__ x, const float* __restrict__ t2, long t2div,
                   const float* __restrict__ w, const float* __restrict__ b)
{
    long r = blockIdx.x;
    float* xr = x + r * WDIM;
    const float* tr = t2 + (r / t2div) * WDIM;
    int tid = threadIdx.x;
    float v0 = xr[tid] + tr[tid];
    float v1 = xr[tid + 256] + tr[tid + 256];
    __shared__ float red[256];
    red[tid] = v0 + v1; __syncthreads();
    for (int off = 128; off > 0; off >>= 1) {
        if (tid < off) red[tid] += red[tid + off];
        __syncthreads();
    }
    float mean = red[0] * (1.f / WDIM); __syncthreads();
    float d0 = v0 - mean, d1 = v1 - mean;
    red[tid] = d0 * d0 + d1 * d1; __syncthreads();
    for (int off = 128; off > 0; off >>= 1) {
        if (tid < off) red[tid] += red[tid + off];
        __syncthreads();
    }
    float rstd = 1.f / sqrtf(red[0] * (1.f / WDIM) + 1e-5f);
    xr[tid]       = d0 * rstd * w[tid] + b[tid];
    xr[tid + 256] = d1 * rstd * w[tid + 256] + b[tid + 256];
}

extern "C" void kernel_launch(void* const* d_in, const int* in_sizes, int n_in,
                              void* d_out, int out_size, void* d_ws, size_t ws_size,
                              hipStream_t stream)
{
    const float* features = (const float*)d_in[0];
    const int*   captions = (const int*)  d_in[1];
    const float* emb      = (const float*)d_in[2];
    const float* pe       = (const float*)d_in[3];
    const float* vis_w    = (const float*)d_in[4];
    const float* vis_b    = (const float*)d_in[5];
    const float* sa_wq    = (const float*)d_in[6];
    const float* sa_bq    = (const float*)d_in[7];
    const float* sa_wk    = (const float*)d_in[8];
    const float* sa_bk    = (const float*)d_in[9];
    const float* sa_wv    = (const float*)d_in[10];
    const float* sa_bv    = (const float*)d_in[11];
    const float* sa_wo    = (const float*)d_in[12];
    const float* sa_bo    = (const float*)d_in[13];
    // ca_wq/bq/wk/bk (14..17) unused: len-1 memory => softmax == 1 identically
    const float* ca_wv    = (const float*)d_in[18];
    const float* ca_bv    = (const float*)d_in[19];
    const float* ca_wo    = (const float*)d_in[20];
    const float* ca_bo    = (const float*)d_in[21];
    const float* ff1_w    = (const float*)d_in[22];
    const float* ff1_b    = (const float*)d_in[23];
    const float* ff2_w    = (const float*)d_in[24];
    const float* ff2_b    = (const float*)d_in[25];
    const float* ln1_w    = (const float*)d_in[26];
    const float* ln1_b    = (const float*)d_in[27];
    const float* ln2_w    = (const float*)d_in[28];
    const float* ln2_b    = (const float*)d_in[29];
    const float* ln3_w    = (const float*)d_in[30];
    const float* ln3_b    = (const float*)d_in[31];
    const float* out_w    = (const float*)d_in[32];
    const float* out_b    = (const float*)d_in[33];

    float* ws   = (float*)d_ws;
    float* x    = ws;                                  // NT*WDIM
    float* t2   = x  + (long)NT * WDIM;                // NT*WDIM
    float* qb   = t2 + (long)NT * WDIM;                // NT*WDIM
    float* kb   = qb + (long)NT * WDIM;                // NT*WDIM
    float* vb   = kb + (long)NT * WDIM;                // NT*WDIM
    float* big  = vb + (long)NT * WDIM;                // max(N*H*T*T, NT*FF) = 8388608
    float* memb = big + 8388608;                       // NBATCH*WDIM
    float* cav  = memb + NBATCH * WDIM;                // NBATCH*WDIM

    auto gemm = [stream](const float* A, int lda, long sAn, long sAh,
                         const float* B, int ldb, long sBn, long sBh,
                         float* C, int ldc, long sCn, long sCh,
                         const float* bias, int M, int N, int K, int HH, int batch,
                         float alpha, bool transB, bool relu)
    {
        dim3 g((N + BN - 1) / BN, (M + BM - 1) / BM, batch), blk(256);
        if (transB)
            gemm_kernel<1, 0><<<g, blk, 0, stream>>>(A, lda, sAn, sAh, B, ldb, sBn, sBh,
                                                     C, ldc, sCn, sCh, bias, M, N, K, HH, alpha);
        else if (relu)
            gemm_kernel<0, 1><<<g, blk, 0, stream>>>(A, lda, sAn, sAh, B, ldb, sBn, sBh,
                                                     C, ldc, sCn, sCh, bias, M, N, K, HH, alpha);
        else
            gemm_kernel<0, 0><<<g, blk, 0, stream>>>(A, lda, sAn, sAh, B, ldb, sBn, sBh,
                                                     C, ldc, sCn, sCh, bias, M, N, K, HH, alpha);
    };

    // memory = features @ vis_w + vis_b   (8 x 512)
    gemm(features, DFEAT, 0, 0, vis_w, WDIM, 0, 0, memb, WDIM, 0, 0,
         vis_b, NBATCH, WDIM, DFEAT, 1, 1, 1.f, false, false);
    // x = emb[captions] + pe
    embed_kernel<<<NT, 128, 0, stream>>>(captions, emb, pe, x);

    const float iscale = 1.f / sqrtf((float)DHEAD);
    for (int l = 0; l < NLAY; l++) {
        long wo  = (long)l * WDIM * WDIM;
        long bo_ = (long)l * WDIM;
        // ---- self-attention ----
        gemm(x, WDIM, 0, 0, sa_wq + wo, WDIM, 0, 0, qb, WDIM, 0, 0,
             sa_bq + bo_, NT, WDIM, WDIM, 1, 1, 1.f, false, false);
        gemm(x, WDIM, 0, 0, sa_wk + wo, WDIM, 0, 0, kb, WDIM, 0, 0,
             sa_bk + bo_, NT, WDIM, WDIM, 1, 1, 1.f, false, false);
        gemm(x, WDIM, 0, 0, sa_wv + wo, WDIM, 0, 0, vb, WDIM, 0, 0,
             sa_bv + bo_, NT, WDIM, WDIM, 1, 1, 1.f, false, false);
        // scores = (Q_h @ K_h^T) * iscale, batched over (n,h)
        gemm(qb, WDIM, (long)TLEN * WDIM, DHEAD,
             kb, WDIM, (long)TLEN * WDIM, DHEAD,
             big, TLEN, (long)NHEADS * TLEN * TLEN, (long)TLEN * TLEN,
             nullptr, TLEN, TLEN, DHEAD, NHEADS, NBATCH * NHEADS, iscale, true, false);
        softmax_causal_kernel<<<NBATCH * NHEADS * TLEN, 256, 0, stream>>>(big);
        // y = P @ V_h  -> reuse qb
        gemm(big, TLEN, (long)NHEADS * TLEN * TLEN, (long)TLEN * TLEN,
             vb, WDIM, (long)TLEN * WDIM, DHEAD,
             qb, WDIM, (long)TLEN * WDIM, DHEAD,
             nullptr, TLEN, DHEAD, TLEN, NHEADS, NBATCH * NHEADS, 1.f, false, false);
        // t2 = y @ wo + bo
        gemm(qb, WDIM, 0, 0, sa_wo + wo, WDIM, 0, 0, t2, WDIM, 0, 0,
             sa_bo + bo_, NT, WDIM, WDIM, 1, 1, 1.f, false, false);
        add_ln_kernel<<<NT, 256, 0, stream>>>(x, t2, 1, ln1_w + bo_, ln1_b + bo_);
        // ---- cross-attention (collapsed: softmax over len-1 == 1) ----
        gemm(memb, WDIM, 0, 0, ca_wv + wo, WDIM, 0, 0, kb, WDIM, 0, 0,
             ca_bv + bo_, NBATCH, WDIM, WDIM, 1, 1, 1.f, false, false);
        gemm(kb, WDIM, 0, 0, ca_wo + wo, WDIM, 0, 0, cav, WDIM, 0, 0,
             ca_bo + bo_, NBATCH, WDIM, WDIM, 1, 1, 1.f, false, false);
        add_ln_kernel<<<NT, 256, 0, stream>>>(x, cav, TLEN, ln2_w + bo_, ln2_b + bo_);
        // ---- FFN ----
        gemm(x, WDIM, 0, 0, ff1_w + (long)l * WDIM * FFDIM, FFDIM, 0, 0,
             big, FFDIM, 0, 0, ff1_b + (long)l * FFDIM,
             NT, FFDIM, WDIM, 1, 1, 1.f, false, true);
        gemm(big, FFDIM, 0, 0, ff2_w + (long)l * FFDIM * WDIM, WDIM, 0, 0,
             t2, WDIM, 0, 0, ff2_b + bo_, NT, WDIM, FFDIM, 1, 1, 1.f, false, false);
        add_ln_kernel<<<NT, 256, 0, stream>>>(x, t2, 1, ln3_w + bo_, ln3_b + bo_);
    }
    // out = x @ out_w + out_b   (4096 x 32000)
    gemm(x, WDIM, 0, 0, out_w, VOCAB, 0, 0, (float*)d_out, VOCAB, 0, 0,
         out_b, NT, VOCAB, WDIM, 1, 1, 1.f, false, false);
}

// Round 2
// 993.446 us; speedup vs baseline: 4.0236x; 4.0236x over previous
//
#include <hip/hip_runtime.h>
#include <math.h>

#define WDIM   512
#define TLEN   512
#define NBATCH 8
#define NHEADS 4
#define DHEAD  128
#define VOCAB  32000
#define NLAY   2
#define FFDIM  2048
#define DFEAT  1024
#define NT     (NBATCH * TLEN)   // 4096 rows

typedef unsigned short u16;
typedef __attribute__((ext_vector_type(8))) short bf16x8;
typedef __attribute__((ext_vector_type(4))) float f32x4;

__device__ inline u16 f2bf(float f) {
    union { float f; unsigned u; } v; v.f = f;
    unsigned r = v.u + 0x7fffu + ((v.u >> 16) & 1u);
    return (u16)(r >> 16);
}

// ---------------- f32 -> bf16 flat convert ----------------
__global__ __launch_bounds__(256)
void cvt_kernel(const float* __restrict__ s, u16* __restrict__ d, int n)
{
    int i = blockIdx.x * 256 + threadIdx.x;
    if (i < n) d[i] = f2bf(s[i]);
}

// ---------------- tiled transpose + convert: src (K,N) f32 -> dst (N,K) bf16 ----------------
__global__ __launch_bounds__(256)
void transpose_cvt_kernel(const float* __restrict__ src, int lds_, long ssn, long ssh,
                          u16* __restrict__ dst, int ldd, long dsn, long dsh,
                          int HH)
{
    int z = blockIdx.z;
    int zn = z / HH, zh = z - zn * HH;
    src += (long)zn * ssn + (long)zh * ssh;
    dst += (long)zn * dsn + (long)zh * dsh;
    __shared__ float tile[32][33];
    int n0 = blockIdx.x * 32, k0 = blockIdx.y * 32;
    int tx = threadIdx.x & 31, ty = threadIdx.x >> 5;  // 32 x 8
    #pragma unroll
    for (int i = 0; i < 32; i += 8)
        tile[ty + i][tx] = src[(long)(k0 + ty + i) * lds_ + n0 + tx];
    __syncthreads();
    #pragma unroll
    for (int i = 0; i < 32; i += 8)
        dst[(long)(n0 + ty + i) * ldd + k0 + tx] = f2bf(tile[tx][ty + i]);
}

// ---------------- embed + positional encoding ----------------
__global__ __launch_bounds__(128)
void embed_kernel(const int* __restrict__ captions, const float* __restrict__ emb,
                  const float* __restrict__ pe, float* __restrict__ x, u16* __restrict__ xb)
{
    int r = blockIdx.x;            // 0..NT-1
    int t = r % TLEN;
    int cap = captions[r];
    const float4* e4 = (const float4*)(emb + (long)cap * WDIM);
    const float4* p4 = (const float4*)(pe + (long)t * WDIM);
    float4 a = e4[threadIdx.x], b = p4[threadIdx.x];
    float4 o = make_float4(a.x + b.x, a.y + b.y, a.z + b.z, a.w + b.w);
    ((float4*)(x + (long)r * WDIM))[threadIdx.x] = o;
    ushort4 ob = make_ushort4(f2bf(o.x), f2bf(o.y), f2bf(o.z), f2bf(o.w));
    ((ushort4*)(xb + (long)r * WDIM))[threadIdx.x] = ob;
}

// ---------------- bf16 MFMA GEMM (m97 structure) ----------------
// C[z] = act(alpha * A[z] @ B[z]^T + bias); A (M,K) bf16 row-major,
// B stored TRANSPOSED (N,K) bf16 row-major. C f32 and/or Cb bf16 outputs.
// batch z decomposed (zn, zh) = (z/HH, z%HH) with separate strides.
// N % 128 == 0, K % 32 == 0 at every call site; M may be ragged (M=8).
#define GBM 128
#define GBN 128
#define GBK 32

template<int RELU>
__global__ __launch_bounds__(256)
void mfma_gemm_kernel(const u16* __restrict__ A, int lda, long sAn, long sAh,
                      const u16* __restrict__ B, int ldb, long sBn, long sBh,
                      float* __restrict__ C, u16* __restrict__ Cb, int ldc, long sCn, long sCh,
                      const float* __restrict__ bias,
                      int M, int N, int K, int HH, float alpha)
{
    int z = blockIdx.z;
    int zn = z / HH, zh = z - zn * HH;
    A += (long)zn * sAn + (long)zh * sAh;
    B += (long)zn * sBn + (long)zh * sBh;
    long coff = (long)zn * sCn + (long)zh * sCh;
    int bm = blockIdx.y * GBM, bn = blockIdx.x * GBN;

    __shared__ u16 As[GBM * GBK];   // [row][k] linear, k contiguous
    __shared__ u16 Bs[GBN * GBK];   // [col][k] linear

    int tid = threadIdx.x;
    int w = tid >> 6, lane = tid & 63;
    int wr = w >> 1, wc = w & 1;         // 2x2 wave grid, 64x64 per wave
    int lrow = lane & 15, kgrp = lane >> 4;

    f32x4 acc[4][4] = {};

    for (int k0 = 0; k0 < K; k0 += GBK) {
        // stage A tile (128x32 bf16 = 8KB): 512 chunks of 16B; chunk c -> row c/4, k (c%4)*8
        #pragma unroll
        for (int i = 0; i < 2; i++) {
            int c = tid + i * 256;
            int row = c >> 2, ko = (c & 3) << 3;
            int gr = bm + row; if (gr >= M) gr = M - 1;   // clamp (ragged M=8 case)
            const u16* src = A + (long)gr * lda + k0 + ko;
            u16* dst = &As[(size_t)(w * 64 + i * 256) * 8];   // wave-uniform base
            __builtin_amdgcn_global_load_lds((const __attribute__((address_space(1))) void*)src,
                                             (__attribute__((address_space(3))) void*)dst, 16, 0, 0);
        }
        #pragma unroll
        for (int i = 0; i < 2; i++) {
            int c = tid + i * 256;
            int row = c >> 2, ko = (c & 3) << 3;
            const u16* src = B + (long)(bn + row) * ldb + k0 + ko;
            u16* dst = &Bs[(size_t)(w * 64 + i * 256) * 8];
            __builtin_amdgcn_global_load_lds((const __attribute__((address_space(1))) void*)src,
                                             (__attribute__((address_space(3))) void*)dst, 16, 0, 0);
        }
        __syncthreads();
        // fragment loads: A row=lane&15, k=(lane>>4)*8+j (contiguous 16B -> ds_read_b128)
        bf16x8 av[4], bv[4];
        #pragma unroll
        for (int m = 0; m < 4; m++)
            av[m] = *(const bf16x8*)&As[(wr * 64 + m * 16 + lrow) * GBK + kgrp * 8];
        #pragma unroll
        for (int n = 0; n < 4; n++)
            bv[n] = *(const bf16x8*)&Bs[(wc * 64 + n * 16 + lrow) * GBK + kgrp * 8];
        #pragma unroll
        for (int m = 0; m < 4; m++)
            #pragma unroll
            for (int n = 0; n < 4; n++)
                acc[m][n] = __builtin_amdgcn_mfma_f32_16x16x32_bf16(av[m], bv[n], acc[m][n], 0, 0, 0);
        __syncthreads();
    }

    if (C)  C  += coff;
    if (Cb) Cb += coff;
    // C/D layout: col = lane&15, row = (lane>>4)*4 + reg   [m89/m91 verified]
    #pragma unroll
    for (int m = 0; m < 4; m++) {
        int rb = bm + wr * 64 + m * 16 + kgrp * 4;
        #pragma unroll
        for (int n = 0; n < 4; n++) {
            int gc = bn + wc * 64 + n * 16 + lrow;
            float bvv = bias ? bias[gc] : 0.f;
            #pragma unroll
            for (int r = 0; r < 4; r++) {
                int gr = rb + r;
                if (gr < M) {
                    float v2 = acc[m][n][r] * alpha + bvv;
                    if (RELU) v2 = fmaxf(v2, 0.f);
                    if (C)  C[(long)gr * ldc + gc]  = v2;
                    if (Cb) Cb[(long)gr * ldc + gc] = f2bf(v2);
                }
            }
        }
    }
}

// ---------------- causal softmax: f32 scores -> bf16 P ----------------
__global__ __launch_bounds__(256)
void softmax_causal_kernel(const float* __restrict__ scores, u16* __restrict__ pb)
{
    long row = blockIdx.x;                 // n*H*T + h*T + s
    int s = (int)(row % TLEN);
    const float* p = scores + row * TLEN;
    u16* o = pb + row * TLEN;
    int tid = threadIdx.x;
    float v0 = p[tid], v1 = p[tid + 256];
    bool m0 = (tid <= s), m1 = (tid + 256 <= s);
    __shared__ float red[256];
    float mx = fmaxf(m0 ? v0 : -INFINITY, m1 ? v1 : -INFINITY);
    red[tid] = mx; __syncthreads();
    for (int off = 128; off > 0; off >>= 1) {
        if (tid < off) red[tid] = fmaxf(red[tid], red[tid + off]);
        __syncthreads();
    }
    mx = red[0]; __syncthreads();
    float e0 = m0 ? expf(v0 - mx) : 0.f;
    float e1 = m1 ? expf(v1 - mx) : 0.f;
    red[tid] = e0 + e1; __syncthreads();
    for (int off = 128; off > 0; off >>= 1) {
        if (tid < off) red[tid] += red[tid + off];
        __syncthreads();
    }
    float inv = 1.f / red[0];
    o[tid]       = f2bf(e0 * inv);
    o[tid + 256] = f2bf(e1 * inv);
}

// ---------------- x = LayerNorm(x + t2); writes f32 x and bf16 xb ----------------
__global__ __launch_bounds__(256)
void add_ln_kernel(float* __restrict__ x, u16* __restrict__ xb,
                   const float* __restrict__ t2, long t2div,
                   const float* __restrict__ w, const float* __restrict__ b)
{
    long r = blockIdx.x;
    float* xr = x + r * WDIM;
    u16* xbr = xb + r * WDIM;
    const float* tr = t2 + (r / t2div) * WDIM;
    int tid = threadIdx.x;
    float v0 = xr[tid] + tr[tid];
    float v1 = xr[tid + 256] + tr[tid + 256];
    __shared__ float red[256];
    red[tid] = v0 + v1; __syncthreads();
    for (int off = 128; off > 0; off >>= 1) {
        if (tid < off) red[tid] += red[tid + off];
        __syncthreads();
    }
    float mean = red[0] * (1.f / WDIM); __syncthreads();
    float d0 = v0 - mean, d1 = v1 - mean;
    red[tid] = d0 * d0 + d1 * d1; __syncthreads();
    for (int off = 128; off > 0; off >>= 1) {
        if (tid < off) red[tid] += red[tid + off];
        __syncthreads();
    }
    float rstd = 1.f / sqrtf(red[0] * (1.f / WDIM) + 1e-5f);
    float o0 = d0 * rstd * w[tid] + b[tid];
    float o1 = d1 * rstd * w[tid + 256] + b[tid + 256];
    xr[tid] = o0;        xr[tid + 256] = o1;
    xbr[tid] = f2bf(o0); xbr[tid + 256] = f2bf(o1);
}

extern "C" void kernel_launch(void* const* d_in, const int* in_sizes, int n_in,
                              void* d_out, int out_size, void* d_ws, size_t ws_size,
                              hipStream_t stream)
{
    const float* features = (const float*)d_in[0];
    const int*   captions = (const int*)  d_in[1];
    const float* emb      = (const float*)d_in[2];
    const float* pe       = (const float*)d_in[3];
    const float* vis_w    = (const float*)d_in[4];
    const float* vis_b    = (const float*)d_in[5];
    const float* sa_wq    = (const float*)d_in[6];
    const float* sa_bq    = (const float*)d_in[7];
    const float* sa_wk    = (const float*)d_in[8];
    const float* sa_bk    = (const float*)d_in[9];
    const float* sa_wv    = (const float*)d_in[10];
    const float* sa_bv    = (const float*)d_in[11];
    const float* sa_wo    = (const float*)d_in[12];
    const float* sa_bo    = (const float*)d_in[13];
    // ca_wq/bq/wk/bk (14..17) unused: len-1 memory => softmax == 1 identically
    const float* ca_wv    = (const float*)d_in[18];
    const float* ca_bv    = (const float*)d_in[19];
    const float* ca_wo    = (const float*)d_in[20];
    const float* ca_bo    = (const float*)d_in[21];
    const float* ff1_w    = (const float*)d_in[22];
    const float* ff1_b    = (const float*)d_in[23];
    const float* ff2_w    = (const float*)d_in[24];
    const float* ff2_b    = (const float*)d_in[25];
    const float* ln1_w    = (const float*)d_in[26];
    const float* ln1_b    = (const float*)d_in[27];
    const float* ln2_w    = (const float*)d_in[28];
    const float* ln2_b    = (const float*)d_in[29];
    const float* ln3_w    = (const float*)d_in[30];
    const float* ln3_b    = (const float*)d_in[31];
    const float* out_w    = (const float*)d_in[32];
    const float* out_b    = (const float*)d_in[33];

    // ---- workspace carve ----
    char* p = (char*)d_ws;
    auto alloc = [&](size_t bytes) { char* r = p; p += (bytes + 255) & ~(size_t)255; return r; };
    float* x    = (float*)alloc((size_t)NT * WDIM * 4);
    float* t2   = (float*)alloc((size_t)NT * WDIM * 4);
    float* vb   = (float*)alloc((size_t)NT * WDIM * 4);
    float* memb = (float*)alloc((size_t)NBATCH * WDIM * 4);
    float* cav  = (float*)alloc((size_t)NBATCH * WDIM * 4);
    // union region: scores f32 (SA phase) | yb bf16 (PV->Oproj) | hb bf16 (FFN) — disjoint lifetimes
    char*  reg1 = alloc((size_t)NBATCH * NHEADS * TLEN * TLEN * 4);
    float* scores = (float*)reg1;
    u16*   yb     = (u16*)reg1;
    u16*   hb     = (u16*)reg1;
    u16* xb    = (u16*)alloc((size_t)NT * WDIM * 2);
    u16* qbb   = (u16*)alloc((size_t)NT * WDIM * 2);
    u16* kbb   = (u16*)alloc((size_t)NT * WDIM * 2);
    u16* vtb   = (u16*)alloc((size_t)NT * WDIM * 2);
    u16* pb    = (u16*)alloc((size_t)NBATCH * NHEADS * TLEN * TLEN * 2);
    u16* featb = (u16*)alloc((size_t)NBATCH * DFEAT * 2);
    u16* membf = (u16*)alloc((size_t)NBATCH * WDIM * 2);
    u16* cvb   = (u16*)alloc((size_t)NBATCH * WDIM * 2);
    u16* vis_wT = (u16*)alloc((size_t)WDIM * DFEAT * 2);
    u16* sa_wqT = (u16*)alloc((size_t)NLAY * WDIM * WDIM * 2);
    u16* sa_wkT = (u16*)alloc((size_t)NLAY * WDIM * WDIM * 2);
    u16* sa_wvT = (u16*)alloc((size_t)NLAY * WDIM * WDIM * 2);
    u16* sa_woT = (u16*)alloc((size_t)NLAY * WDIM * WDIM * 2);
    u16* ca_wvT = (u16*)alloc((size_t)NLAY * WDIM * WDIM * 2);
    u16* ca_woT = (u16*)alloc((size_t)NLAY * WDIM * WDIM * 2);
    u16* ff1T   = (u16*)alloc((size_t)NLAY * WDIM * FFDIM * 2);
    u16* ff2T   = (u16*)alloc((size_t)NLAY * FFDIM * WDIM * 2);
    u16* out_wT = (u16*)alloc((size_t)WDIM * VOCAB * 2);

    auto gemm = [&](const u16* A, int lda, long sAn, long sAh,
                    const u16* B, int ldb, long sBn, long sBh,
                    float* C, u16* Cb, int ldc, long sCn, long sCh,
                    const float* bias, int M, int N, int K, int HH, int batch,
                    float alpha, bool relu)
    {
        dim3 g(N / GBN, (M + GBM - 1) / GBM, batch), blk(256);
        if (relu)
            mfma_gemm_kernel<1><<<g, blk, 0, stream>>>(A, lda, sAn, sAh, B, ldb, sBn, sBh,
                                                       C, Cb, ldc, sCn, sCh, bias, M, N, K, HH, alpha);
        else
            mfma_gemm_kernel<0><<<g, blk, 0, stream>>>(A, lda, sAn, sAh, B, ldb, sBn, sBh,
                                                       C, Cb, ldc, sCn, sCh, bias, M, N, K, HH, alpha);
    };
    auto transpose = [&](const float* src, int lds_, long ssn, long ssh,
                         u16* dst, int ldd, long dsn, long dsh,
                         int K, int N, int batch, int HH)
    {
        dim3 g(N / 32, K / 32, batch), blk(256);
        transpose_cvt_kernel<<<g, blk, 0, stream>>>(src, lds_, ssn, ssh, dst, ldd, dsn, dsh, HH);
    };

    // ---- weight conversion (per call; deterministic) ----
    cvt_kernel<<<(NBATCH * DFEAT + 255) / 256, 256, 0, stream>>>(features, featb, NBATCH * DFEAT);
    transpose(vis_w, WDIM, 0, 0, vis_wT, DFEAT, 0, 0, DFEAT, WDIM, 1, 1);
    transpose(sa_wq, WDIM, (long)WDIM * WDIM, 0, sa_wqT, WDIM, (long)WDIM * WDIM, 0, WDIM, WDIM, NLAY, 1);
    transpose(sa_wk, WDIM, (long)WDIM * WDIM, 0, sa_wkT, WDIM, (long)WDIM * WDIM, 0, WDIM, WDIM, NLAY, 1);
    transpose(sa_wv, WDIM, (long)WDIM * WDIM, 0, sa_wvT, WDIM, (long)WDIM * WDIM, 0, WDIM, WDIM, NLAY, 1);
    transpose(sa_wo, WDIM, (long)WDIM * WDIM, 0, sa_woT, WDIM, (long)WDIM * WDIM, 0, WDIM, WDIM, NLAY, 1);
    transpose(ca_wv, WDIM, (long)WDIM * WDIM, 0, ca_wvT, WDIM, (long)WDIM * WDIM, 0, WDIM, WDIM, NLAY, 1);
    transpose(ca_wo, WDIM, (long)WDIM * WDIM, 0, ca_woT, WDIM, (long)WDIM * WDIM, 0, WDIM, WDIM, NLAY, 1);
    transpose(ff1_w, FFDIM, (long)WDIM * FFDIM, 0, ff1T, WDIM, (long)FFDIM * WDIM, 0, WDIM, FFDIM, NLAY, 1);
    transpose(ff2_w, WDIM, (long)FFDIM * WDIM, 0, ff2T, FFDIM, (long)WDIM * FFDIM, 0, FFDIM, WDIM, NLAY, 1);
    transpose(out_w, VOCAB, 0, 0, out_wT, WDIM, 0, 0, WDIM, VOCAB, 1, 1);

    // memory = features @ vis_w + vis_b   (8 x 512), keep f32 + bf16
    gemm(featb, DFEAT, 0, 0, vis_wT, DFEAT, 0, 0, memb, membf, WDIM, 0, 0,
         vis_b, NBATCH, WDIM, DFEAT, 1, 1, 1.f, false);
    // x = emb[captions] + pe
    embed_kernel<<<NT, 128, 0, stream>>>(captions, emb, pe, x, xb);

    const float iscale = 1.f / sqrtf((float)DHEAD);
    const long TW = (long)TLEN * WDIM;
    const long TT = (long)TLEN * TLEN;
    for (int l = 0; l < NLAY; l++) {
        long wo  = (long)l * WDIM * WDIM;
        long bo_ = (long)l * WDIM;
        // ---- self-attention ----
        gemm(xb, WDIM, 0, 0, sa_wqT + wo, WDIM, 0, 0, nullptr, qbb, WDIM, 0, 0,
             sa_bq + bo_, NT, WDIM, WDIM, 1, 1, 1.f, false);
        gemm(xb, WDIM, 0, 0, sa_wkT + wo, WDIM, 0, 0, nullptr, kbb, WDIM, 0, 0,
             sa_bk + bo_, NT, WDIM, WDIM, 1, 1, 1.f, false);
        gemm(xb, WDIM, 0, 0, sa_wvT + wo, WDIM, 0, 0, vb, nullptr, WDIM, 0, 0,
             sa_bv + bo_, NT, WDIM, WDIM, 1, 1, 1.f, false);
        // V^T per (n,h): vb [n][t][h*128+d] -> vtb [n][h][d][t]
        transpose(vb, WDIM, TW, DHEAD, vtb, TLEN, (long)NHEADS * DHEAD * TLEN, (long)DHEAD * TLEN,
                  TLEN, DHEAD, NBATCH * NHEADS, NHEADS);
        // scores = (Q_h @ K_h^T) * iscale
        gemm(qbb, WDIM, TW, DHEAD, kbb, WDIM, TW, DHEAD,
             scores, nullptr, TLEN, (long)NHEADS * TT, TT,
             nullptr, TLEN, TLEN, DHEAD, NHEADS, NBATCH * NHEADS, iscale, false);
        softmax_causal_kernel<<<NBATCH * NHEADS * TLEN, 256, 0, stream>>>(scores, pb);
        // y = P @ V_h  (B = V^T tile, (N=d, K=t))
        gemm(pb, TLEN, (long)NHEADS * TT, TT,
             vtb, TLEN, (long)NHEADS * DHEAD * TLEN, (long)DHEAD * TLEN,
             nullptr, yb, WDIM, TW, DHEAD,
             nullptr, TLEN, DHEAD, TLEN, NHEADS, NBATCH * NHEADS, 1.f, false);
        // t2 = y @ wo + bo
        gemm(yb, WDIM, 0, 0, sa_woT + wo, WDIM, 0, 0, t2, nullptr, WDIM, 0, 0,
             sa_bo + bo_, NT, WDIM, WDIM, 1, 1, 1.f, false);
        add_ln_kernel<<<NT, 256, 0, stream>>>(x, xb, t2, 1, ln1_w + bo_, ln1_b + bo_);
        // ---- cross-attention (collapsed: softmax over len-1 == 1) ----
        gemm(membf, WDIM, 0, 0, ca_wvT + wo, WDIM, 0, 0, nullptr, cvb, WDIM, 0, 0,
             ca_bv + bo_, NBATCH, WDIM, WDIM, 1, 1, 1.f, false);
        gemm(cvb, WDIM, 0, 0, ca_woT + wo, WDIM, 0, 0, cav, nullptr, WDIM, 0, 0,
             ca_bo + bo_, NBATCH, WDIM, WDIM, 1, 1, 1.f, false);
        add_ln_kernel<<<NT, 256, 0, stream>>>(x, xb, cav, TLEN, ln2_w + bo_, ln2_b + bo_);
        // ---- FFN ----
        gemm(xb, WDIM, 0, 0, ff1T + (long)l * FFDIM * WDIM, WDIM, 0, 0,
             nullptr, hb, FFDIM, 0, 0, ff1_b + (long)l * FFDIM,
             NT, FFDIM, WDIM, 1, 1, 1.f, true);
        gemm(hb, FFDIM, 0, 0, ff2T + (long)l * WDIM * FFDIM, FFDIM, 0, 0,
             t2, nullptr, WDIM, 0, 0, ff2_b + bo_, NT, WDIM, FFDIM, 1, 1, 1.f, false);
        add_ln_kernel<<<NT, 256, 0, stream>>>(x, xb, t2, 1, ln3_w + bo_, ln3_b + bo_);
    }
    // out = x @ out_w + out_b   (4096 x 32000)
    gemm(xb, WDIM, 0, 0, out_wT, WDIM, 0, 0, (float*)d_out, nullptr, VOCAB, 0, 0,
         out_b, NT, VOCAB, WDIM, 1, 1, 1.f, false);
}

// Round 3
// 962.375 us; speedup vs baseline: 4.1535x; 1.0323x over previous
//
#include <hip/hip_runtime.h>
#include <math.h>

#define WDIM   512
#define TLEN   512
#define NBATCH 8
#define NHEADS 4
#define DHEAD  128
#define VOCAB  32000
#define NLAY   2
#define FFDIM  2048
#define DFEAT  1024
#define NT     (NBATCH * TLEN)   // 4096 rows
#define QKVW   (3 * WDIM)        // 1536

typedef unsigned short u16;
typedef __attribute__((ext_vector_type(8))) short bf16x8;
typedef __attribute__((ext_vector_type(4))) float f32x4;

__device__ inline u16 f2bf(float f) {
    union { float f; unsigned u; } v; v.f = f;
    unsigned r = v.u + 0x7fffu + ((v.u >> 16) & 1u);
    return (u16)(r >> 16);
}
__device__ inline u16 to_bf(float f) { return f2bf(f); }
__device__ inline u16 to_bf(u16 v)  { return v; }

// ---------------- f32 -> bf16 flat convert ----------------
__global__ __launch_bounds__(256)
void cvt_kernel(const float* __restrict__ s, u16* __restrict__ d, int n)
{
    int i = blockIdx.x * 256 + threadIdx.x;
    if (i < n) d[i] = f2bf(s[i]);
}

// ---------------- concat per-layer QKV bias: [bq;bk;bv] -> (NLAY,1536) ----------------
__global__ __launch_bounds__(256)
void concat_bias_kernel(const float* __restrict__ bq, const float* __restrict__ bk,
                        const float* __restrict__ bv, float* __restrict__ dst)
{
    int i = blockIdx.x * 256 + threadIdx.x;
    if (i >= NLAY * QKVW) return;
    int l = i / QKVW, j = i - l * QKVW;
    float v = (j < WDIM) ? bq[l * WDIM + j]
            : (j < 2 * WDIM) ? bk[l * WDIM + j - WDIM]
            : bv[l * WDIM + j - 2 * WDIM];
    dst[i] = v;
}

// ---------------- tiled transpose + convert: src (K,N) -> dst (N,K) bf16 ----------------
template<typename T>
__global__ __launch_bounds__(256)
void transpose_cvt_kernel(const T* __restrict__ src, int lds_, long ssn, long ssh,
                          u16* __restrict__ dst, int ldd, long dsn, long dsh,
                          int HH)
{
    int z = blockIdx.z;
    int zn = z / HH, zh = z - zn * HH;
    src += (long)zn * ssn + (long)zh * ssh;
    dst += (long)zn * dsn + (long)zh * dsh;
    __shared__ T tile[32][33];
    int n0 = blockIdx.x * 32, k0 = blockIdx.y * 32;
    int tx = threadIdx.x & 31, ty = threadIdx.x >> 5;  // 32 x 8
    #pragma unroll
    for (int i = 0; i < 32; i += 8)
        tile[ty + i][tx] = src[(long)(k0 + ty + i) * lds_ + n0 + tx];
    __syncthreads();
    #pragma unroll
    for (int i = 0; i < 32; i += 8)
        dst[(long)(n0 + ty + i) * ldd + k0 + tx] = to_bf(tile[tx][ty + i]);
}

// ---------------- embed + positional encoding ----------------
__global__ __launch_bounds__(128)
void embed_kernel(const int* __restrict__ captions, const float* __restrict__ emb,
                  const float* __restrict__ pe, float* __restrict__ x, u16* __restrict__ xb)
{
    int r = blockIdx.x;            // 0..NT-1
    int t = r % TLEN;
    int cap = captions[r];
    const float4* e4 = (const float4*)(emb + (long)cap * WDIM);
    const float4* p4 = (const float4*)(pe + (long)t * WDIM);
    float4 a = e4[threadIdx.x], b = p4[threadIdx.x];
    float4 o = make_float4(a.x + b.x, a.y + b.y, a.z + b.z, a.w + b.w);
    ((float4*)(x + (long)r * WDIM))[threadIdx.x] = o;
    ushort4 ob = make_ushort4(f2bf(o.x), f2bf(o.y), f2bf(o.z), f2bf(o.w));
    ((ushort4*)(xb + (long)r * WDIM))[threadIdx.x] = ob;
}

// ---------------- bf16 MFMA GEMM (m97 structure + XCD-chunked swizzle) ----------------
// C[z] = act(alpha * A[z] @ B[z]^T + bias); A (M,K) bf16 row-major,
// B stored TRANSPOSED (N,K) bf16 row-major. C f32 and/or Cb bf16 outputs.
// batch z decomposed (zn, zh) = (z/HH, z%HH) with separate strides.
// N % 128 == 0, K % 32 == 0 at every call site; M may be ragged (M=8).
#define GBM 128
#define GBN 128
#define GBK 32

template<int RELU>
__global__ __launch_bounds__(256)
void mfma_gemm_kernel(const u16* __restrict__ A, int lda, long sAn, long sAh,
                      const u16* __restrict__ B, int ldb, long sBn, long sBh,
                      float* __restrict__ C, u16* __restrict__ Cb, int ldc, long sCn, long sCh,
                      const float* __restrict__ bias,
                      int M, int N, int K, int HH, float alpha)
{
    int z = blockIdx.z;
    int zn = z / HH, zh = z - zn * HH;
    A += (long)zn * sAn + (long)zh * sAh;
    B += (long)zn * sBn + (long)zh * sBh;
    long coff = (long)zn * sCn + (long)zh * sCh;

    // XCD-chunked bijective swizzle (m204): hardware assigns orig%8 -> XCD.
    // Remap so each XCD gets a contiguous chunk of (bx-major) tile space:
    // all M-blocks sharing one B panel land on ONE XCD -> B-panel L2 reuse.
    int nwg  = gridDim.x * gridDim.y;
    int orig = blockIdx.y * gridDim.x + blockIdx.x;
    int q = nwg >> 3, r = nwg & 7, xcd = orig & 7, rest = orig >> 3;
    int nw = (xcd < r ? xcd * (q + 1) : r * (q + 1) + (xcd - r) * q) + rest;
    int bx = nw / gridDim.y, by = nw - bx * gridDim.y;
    int bm = by * GBM, bn = bx * GBN;

    __shared__ u16 As[GBM * GBK];   // [row][k] linear, k contiguous
    __shared__ u16 Bs[GBN * GBK];   // [col][k] linear

    int tid = threadIdx.x;
    int w = tid >> 6, lane = tid & 63;
    int wr = w >> 1, wc = w & 1;         // 2x2 wave grid, 64x64 per wave
    int lrow = lane & 15, kgrp = lane >> 4;

    f32x4 acc[4][4] = {};

    for (int k0 = 0; k0 < K; k0 += GBK) {
        // stage A tile (128x32 bf16 = 8KB): 512 chunks of 16B; chunk c -> row c/4, k (c%4)*8
        #pragma unroll
        for (int i = 0; i < 2; i++) {
            int c = tid + i * 256;
            int row = c >> 2, ko = (c & 3) << 3;
            int gr = bm + row; if (gr >= M) gr = M - 1;   // clamp (ragged M=8 case)
            const u16* src = A + (long)gr * lda + k0 + ko;
            u16* dst = &As[(size_t)(w * 64 + i * 256) * 8];   // wave-uniform base
            __builtin_amdgcn_global_load_lds((const __attribute__((address_space(1))) void*)src,
                                             (__attribute__((address_space(3))) void*)dst, 16, 0, 0);
        }
        #pragma unroll
        for (int i = 0; i < 2; i++) {
            int c = tid + i * 256;
            int row = c >> 2, ko = (c & 3) << 3;
            const u16* src = B + (long)(bn + row) * ldb + k0 + ko;
            u16* dst = &Bs[(size_t)(w * 64 + i * 256) * 8];
            __builtin_amdgcn_global_load_lds((const __attribute__((address_space(1))) void*)src,
                                             (__attribute__((address_space(3))) void*)dst, 16, 0, 0);
        }
        __syncthreads();
        // fragment loads: A row=lane&15, k=(lane>>4)*8+j (contiguous 16B -> ds_read_b128)
        bf16x8 av[4], bv[4];
        #pragma unroll
        for (int m = 0; m < 4; m++)
            av[m] = *(const bf16x8*)&As[(wr * 64 + m * 16 + lrow) * GBK + kgrp * 8];
        #pragma unroll
        for (int n = 0; n < 4; n++)
            bv[n] = *(const bf16x8*)&Bs[(wc * 64 + n * 16 + lrow) * GBK + kgrp * 8];
        #pragma unroll
        for (int m = 0; m < 4; m++)
            #pragma unroll
            for (int n = 0; n < 4; n++)
                acc[m][n] = __builtin_amdgcn_mfma_f32_16x16x32_bf16(av[m], bv[n], acc[m][n], 0, 0, 0);
        __syncthreads();
    }

    if (C)  C  += coff;
    if (Cb) Cb += coff;
    // C/D layout: col = lane&15, row = (lane>>4)*4 + reg   [m89/m91 verified]
    #pragma unroll
    for (int m = 0; m < 4; m++) {
        int rb = bm + wr * 64 + m * 16 + kgrp * 4;
        #pragma unroll
        for (int n = 0; n < 4; n++) {
            int gc = bn + wc * 64 + n * 16 + lrow;
            float bvv = bias ? bias[gc] : 0.f;
            #pragma unroll
            for (int r2 = 0; r2 < 4; r2++) {
                int gr = rb + r2;
                if (gr < M) {
                    float v2 = acc[m][n][r2] * alpha + bvv;
                    if (RELU) v2 = fmaxf(v2, 0.f);
                    if (C)  C[(long)gr * ldc + gc]  = v2;
                    if (Cb) Cb[(long)gr * ldc + gc] = f2bf(v2);
                }
            }
        }
    }
}

// ---------------- causal softmax: f32 scores -> bf16 P ----------------
__global__ __launch_bounds__(256)
void softmax_causal_kernel(const float* __restrict__ scores, u16* __restrict__ pb)
{
    long row = blockIdx.x;                 // n*H*T + h*T + s
    int s = (int)(row % TLEN);
    const float* p = scores + row * TLEN;
    u16* o = pb + row * TLEN;
    int tid = threadIdx.x;
    float v0 = p[tid], v1 = p[tid + 256];
    bool m0 = (tid <= s), m1 = (tid + 256 <= s);
    __shared__ float red[256];
    float mx = fmaxf(m0 ? v0 : -INFINITY, m1 ? v1 : -INFINITY);
    red[tid] = mx; __syncthreads();
    for (int off = 128; off > 0; off >>= 1) {
        if (tid < off) red[tid] = fmaxf(red[tid], red[tid + off]);
        __syncthreads();
    }
    mx = red[0]; __syncthreads();
    float e0 = m0 ? expf(v0 - mx) : 0.f;
    float e1 = m1 ? expf(v1 - mx) : 0.f;
    red[tid] = e0 + e1; __syncthreads();
    for (int off = 128; off > 0; off >>= 1) {
        if (tid < off) red[tid] += red[tid + off];
        __syncthreads();
    }
    float inv = 1.f / red[0];
    o[tid]       = f2bf(e0 * inv);
    o[tid + 256] = f2bf(e1 * inv);
}

// ---------------- x = LayerNorm(x + t2); writes f32 x and bf16 xb ----------------
__global__ __launch_bounds__(256)
void add_ln_kernel(float* __restrict__ x, u16* __restrict__ xb,
                   const float* __restrict__ t2, long t2div,
                   const float* __restrict__ w, const float* __restrict__ b)
{
    long r = blockIdx.x;
    float* xr = x + r * WDIM;
    u16* xbr = xb + r * WDIM;
    const float* tr = t2 + (r / t2div) * WDIM;
    int tid = threadIdx.x;
    float v0 = xr[tid] + tr[tid];
    float v1 = xr[tid + 256] + tr[tid + 256];
    __shared__ float red[256];
    red[tid] = v0 + v1; __syncthreads();
    for (int off = 128; off > 0; off >>= 1) {
        if (tid < off) red[tid] += red[tid + off];
        __syncthreads();
    }
    float mean = red[0] * (1.f / WDIM); __syncthreads();
    float d0 = v0 - mean, d1 = v1 - mean;
    red[tid] = d0 * d0 + d1 * d1; __syncthreads();
    for (int off = 128; off > 0; off >>= 1) {
        if (tid < off) red[tid] += red[tid + off];
        __syncthreads();
    }
    float rstd = 1.f / sqrtf(red[0] * (1.f / WDIM) + 1e-5f);
    float o0 = d0 * rstd * w[tid] + b[tid];
    float o1 = d1 * rstd * w[tid + 256] + b[tid + 256];
    xr[tid] = o0;        xr[tid + 256] = o1;
    xbr[tid] = f2bf(o0); xbr[tid + 256] = f2bf(o1);
}

extern "C" void kernel_launch(void* const* d_in, const int* in_sizes, int n_in,
                              void* d_out, int out_size, void* d_ws, size_t ws_size,
                              hipStream_t stream)
{
    const float* features = (const float*)d_in[0];
    const int*   captions = (const int*)  d_in[1];
    const float* emb      = (const float*)d_in[2];
    const float* pe       = (const float*)d_in[3];
    const float* vis_w    = (const float*)d_in[4];
    const float* vis_b    = (const float*)d_in[5];
    const float* sa_wq    = (const float*)d_in[6];
    const float* sa_bq    = (const float*)d_in[7];
    const float* sa_wk    = (const float*)d_in[8];
    const float* sa_bk    = (const float*)d_in[9];
    const float* sa_wv    = (const float*)d_in[10];
    const float* sa_bv    = (const float*)d_in[11];
    const float* sa_wo    = (const float*)d_in[12];
    const float* sa_bo    = (const float*)d_in[13];
    // ca_wq/bq/wk/bk (14..17) unused: len-1 memory => softmax == 1 identically
    const float* ca_wv    = (const float*)d_in[18];
    const float* ca_bv    = (const float*)d_in[19];
    const float* ca_wo    = (const float*)d_in[20];
    const float* ca_bo    = (const float*)d_in[21];
    const float* ff1_w    = (const float*)d_in[22];
    const float* ff1_b    = (const float*)d_in[23];
    const float* ff2_w    = (const float*)d_in[24];
    const float* ff2_b    = (const float*)d_in[25];
    const float* ln1_w    = (const float*)d_in[26];
    const float* ln1_b    = (const float*)d_in[27];
    const float* ln2_w    = (const float*)d_in[28];
    const float* ln2_b    = (const float*)d_in[29];
    const float* ln3_w    = (const float*)d_in[30];
    const float* ln3_b    = (const float*)d_in[31];
    const float* out_w    = (const float*)d_in[32];
    const float* out_b    = (const float*)d_in[33];

    // ---- workspace carve ----
    char* p = (char*)d_ws;
    auto alloc = [&](size_t bytes) { char* r = p; p += (bytes + 255) & ~(size_t)255; return r; };
    float* x    = (float*)alloc((size_t)NT * WDIM * 4);
    float* t2   = (float*)alloc((size_t)NT * WDIM * 4);
    float* memb = (float*)alloc((size_t)NBATCH * WDIM * 4);
    float* cav  = (float*)alloc((size_t)NBATCH * WDIM * 4);
    // union region: scores f32 (SA phase) | yb bf16 (PV->Oproj) | hb bf16 (FFN) — disjoint lifetimes
    char*  reg1 = alloc((size_t)NBATCH * NHEADS * TLEN * TLEN * 4);
    float* scores = (float*)reg1;
    u16*   yb     = (u16*)reg1;
    u16*   hb     = (u16*)reg1;
    u16* xb    = (u16*)alloc((size_t)NT * WDIM * 2);
    u16* qkvb  = (u16*)alloc((size_t)NT * QKVW * 2);
    u16* vtb   = (u16*)alloc((size_t)NT * WDIM * 2);
    u16* pb    = (u16*)alloc((size_t)NBATCH * NHEADS * TLEN * TLEN * 2);
    u16* featb = (u16*)alloc((size_t)NBATCH * DFEAT * 2);
    u16* membf = (u16*)alloc((size_t)NBATCH * WDIM * 2);
    u16* cvb   = (u16*)alloc((size_t)NBATCH * WDIM * 2);
    float* qkv_bias = (float*)alloc((size_t)NLAY * QKVW * 4);
    u16* vis_wT = (u16*)alloc((size_t)WDIM * DFEAT * 2);
    u16* qkvT   = (u16*)alloc((size_t)NLAY * QKVW * WDIM * 2);
    u16* sa_woT = (u16*)alloc((size_t)NLAY * WDIM * WDIM * 2);
    u16* ca_wvT = (u16*)alloc((size_t)NLAY * WDIM * WDIM * 2);
    u16* ca_woT = (u16*)alloc((size_t)NLAY * WDIM * WDIM * 2);
    u16* ff1T   = (u16*)alloc((size_t)NLAY * WDIM * FFDIM * 2);
    u16* ff2T   = (u16*)alloc((size_t)NLAY * FFDIM * WDIM * 2);
    u16* out_wT = (u16*)alloc((size_t)WDIM * VOCAB * 2);

    auto gemm = [&](const u16* A, int lda, long sAn, long sAh,
                    const u16* B, int ldb, long sBn, long sBh,
                    float* C, u16* Cb, int ldc, long sCn, long sCh,
                    const float* bias, int M, int N, int K, int HH, int batch,
                    float alpha, bool relu)
    {
        dim3 g(N / GBN, (M + GBM - 1) / GBM, batch), blk(256);
        if (relu)
            mfma_gemm_kernel<1><<<g, blk, 0, stream>>>(A, lda, sAn, sAh, B, ldb, sBn, sBh,
                                                       C, Cb, ldc, sCn, sCh, bias, M, N, K, HH, alpha);
        else
            mfma_gemm_kernel<0><<<g, blk, 0, stream>>>(A, lda, sAn, sAh, B, ldb, sBn, sBh,
                                                       C, Cb, ldc, sCn, sCh, bias, M, N, K, HH, alpha);
    };
    auto transposeF = [&](const float* src, int lds_, long ssn, long ssh,
                          u16* dst, int ldd, long dsn, long dsh,
                          int K, int N, int batch, int HH)
    {
        dim3 g(N / 32, K / 32, batch), blk(256);
        transpose_cvt_kernel<float><<<g, blk, 0, stream>>>(src, lds_, ssn, ssh, dst, ldd, dsn, dsh, HH);
    };
    auto transposeB = [&](const u16* src, int lds_, long ssn, long ssh,
                          u16* dst, int ldd, long dsn, long dsh,
                          int K, int N, int batch, int HH)
    {
        dim3 g(N / 32, K / 32, batch), blk(256);
        transpose_cvt_kernel<u16><<<g, blk, 0, stream>>>(src, lds_, ssn, ssh, dst, ldd, dsn, dsh, HH);
    };

    // ---- weight conversion (per call; deterministic) ----
    cvt_kernel<<<(NBATCH * DFEAT + 255) / 256, 256, 0, stream>>>(features, featb, NBATCH * DFEAT);
    concat_bias_kernel<<<(NLAY * QKVW + 255) / 256, 256, 0, stream>>>(sa_bq, sa_bk, sa_bv, qkv_bias);
    transposeF(vis_w, WDIM, 0, 0, vis_wT, DFEAT, 0, 0, DFEAT, WDIM, 1, 1);
    // fused QKV weight: rows [0,512)=wq^T, [512,1024)=wk^T, [1024,1536)=wv^T per layer
    transposeF(sa_wq, WDIM, (long)WDIM * WDIM, 0, qkvT,                WDIM, (long)QKVW * WDIM, 0, WDIM, WDIM, NLAY, 1);
    transposeF(sa_wk, WDIM, (long)WDIM * WDIM, 0, qkvT + (long)WDIM * WDIM,     WDIM, (long)QKVW * WDIM, 0, WDIM, WDIM, NLAY, 1);
    transposeF(sa_wv, WDIM, (long)WDIM * WDIM, 0, qkvT + (long)2 * WDIM * WDIM, WDIM, (long)QKVW * WDIM, 0, WDIM, WDIM, NLAY, 1);
    transposeF(sa_wo, WDIM, (long)WDIM * WDIM, 0, sa_woT, WDIM, (long)WDIM * WDIM, 0, WDIM, WDIM, NLAY, 1);
    transposeF(ca_wv, WDIM, (long)WDIM * WDIM, 0, ca_wvT, WDIM, (long)WDIM * WDIM, 0, WDIM, WDIM, NLAY, 1);
    transposeF(ca_wo, WDIM, (long)WDIM * WDIM, 0, ca_woT, WDIM, (long)WDIM * WDIM, 0, WDIM, WDIM, NLAY, 1);
    transposeF(ff1_w, FFDIM, (long)WDIM * FFDIM, 0, ff1T, WDIM, (long)FFDIM * WDIM, 0, WDIM, FFDIM, NLAY, 1);
    transposeF(ff2_w, WDIM, (long)FFDIM * WDIM, 0, ff2T, FFDIM, (long)WDIM * FFDIM, 0, FFDIM, WDIM, NLAY, 1);
    transposeF(out_w, VOCAB, 0, 0, out_wT, WDIM, 0, 0, WDIM, VOCAB, 1, 1);

    // memory = features @ vis_w + vis_b   (8 x 512), keep f32 + bf16
    gemm(featb, DFEAT, 0, 0, vis_wT, DFEAT, 0, 0, memb, membf, WDIM, 0, 0,
         vis_b, NBATCH, WDIM, DFEAT, 1, 1, 1.f, false);
    // x = emb[captions] + pe
    embed_kernel<<<NT, 128, 0, stream>>>(captions, emb, pe, x, xb);

    const float iscale = 1.f / sqrtf((float)DHEAD);
    const long TQ = (long)TLEN * QKVW;
    const long TW = (long)TLEN * WDIM;
    const long TT = (long)TLEN * TLEN;
    for (int l = 0; l < NLAY; l++) {
        long wo  = (long)l * WDIM * WDIM;
        long bo_ = (long)l * WDIM;
        // ---- self-attention: fused QKV projection (N=1536) ----
        gemm(xb, WDIM, 0, 0, qkvT + (long)l * QKVW * WDIM, WDIM, 0, 0,
             nullptr, qkvb, QKVW, 0, 0, qkv_bias + (long)l * QKVW,
             NT, QKVW, WDIM, 1, 1, 1.f, false);
        // V^T per (n,h): qkvb[n*T+t][1024 + h*128 + d] -> vtb [n][h][d][t]
        transposeB(qkvb + 2 * WDIM, QKVW, TQ, DHEAD,
                   vtb, TLEN, (long)NHEADS * DHEAD * TLEN, (long)DHEAD * TLEN,
                   TLEN, DHEAD, NBATCH * NHEADS, NHEADS);
        // scores = (Q_h @ K_h^T) * iscale
        gemm(qkvb, QKVW, TQ, DHEAD, qkvb + WDIM, QKVW, TQ, DHEAD,
             scores, nullptr, TLEN, (long)NHEADS * TT, TT,
             nullptr, TLEN, TLEN, DHEAD, NHEADS, NBATCH * NHEADS, iscale, false);
        softmax_causal_kernel<<<NBATCH * NHEADS * TLEN, 256, 0, stream>>>(scores, pb);
        // y = P @ V_h  (B = V^T tile, (N=d, K=t))
        gemm(pb, TLEN, (long)NHEADS * TT, TT,
             vtb, TLEN, (long)NHEADS * DHEAD * TLEN, (long)DHEAD * TLEN,
             nullptr, yb, WDIM, TW, DHEAD,
             nullptr, TLEN, DHEAD, TLEN, NHEADS, NBATCH * NHEADS, 1.f, false);
        // t2 = y @ wo + bo
        gemm(yb, WDIM, 0, 0, sa_woT + wo, WDIM, 0, 0, t2, nullptr, WDIM, 0, 0,
             sa_bo + bo_, NT, WDIM, WDIM, 1, 1, 1.f, false);
        add_ln_kernel<<<NT, 256, 0, stream>>>(x, xb, t2, 1, ln1_w + bo_, ln1_b + bo_);
        // ---- cross-attention (collapsed: softmax over len-1 == 1) ----
        gemm(membf, WDIM, 0, 0, ca_wvT + wo, WDIM, 0, 0, nullptr, cvb, WDIM, 0, 0,
             ca_bv + bo_, NBATCH, WDIM, WDIM, 1, 1, 1.f, false);
        gemm(cvb, WDIM, 0, 0, ca_woT + wo, WDIM, 0, 0, cav, nullptr, WDIM, 0, 0,
             ca_bo + bo_, NBATCH, WDIM, WDIM, 1, 1, 1.f, false);
        add_ln_kernel<<<NT, 256, 0, stream>>>(x, xb, cav, TLEN, ln2_w + bo_, ln2_b + bo_);
        // ---- FFN ----
        gemm(xb, WDIM, 0, 0, ff1T + (long)l * FFDIM * WDIM, WDIM, 0, 0,
             nullptr, hb, FFDIM, 0, 0, ff1_b + (long)l * FFDIM,
             NT, FFDIM, WDIM, 1, 1, 1.f, true);
        gemm(hb, FFDIM, 0, 0, ff2T + (long)l * WDIM * FFDIM, FFDIM, 0, 0,
             t2, nullptr, WDIM, 0, 0, ff2_b + bo_, NT, WDIM, FFDIM, 1, 1, 1.f, false);
        add_ln_kernel<<<NT, 256, 0, stream>>>(x, xb, t2, 1, ln3_w + bo_, ln3_b + bo_);
    }
    // out = x @ out_w + out_b   (4096 x 32000)
    gemm(xb, WDIM, 0, 0, out_wT, WDIM, 0, 0, (float*)d_out, nullptr, VOCAB, 0, 0,
         out_b, NT, VOCAB, WDIM, 1, 1, 1.f, false);
}

// Round 4
// 868.765 us; speedup vs baseline: 4.6010x; 1.1077x over previous
//
#include <hip/hip_runtime.h>
#include <math.h>

#define WDIM   512
#define TLEN   512
#define NBATCH 8
#define NHEADS 4
#define DHEAD  128
#define VOCAB  32000
#define NLAY   2
#define FFDIM  2048
#define DFEAT  1024
#define NT     (NBATCH * TLEN)   // 4096 rows
#define QKVW   (3 * WDIM)        // 1536

typedef unsigned short u16;
typedef __attribute__((ext_vector_type(8))) short bf16x8;
typedef __attribute__((ext_vector_type(4))) float f32x4;

__device__ inline u16 f2bf(float f) {
    union { float f; unsigned u; } v; v.f = f;
    unsigned r = v.u + 0x7fffu + ((v.u >> 16) & 1u);
    return (u16)(r >> 16);
}
__device__ inline u16 to_bf(float f) { return f2bf(f); }
__device__ inline u16 to_bf(u16 v)  { return v; }

// ---------------- f32 -> bf16 flat convert ----------------
__global__ __launch_bounds__(256)
void cvt_kernel(const float* __restrict__ s, u16* __restrict__ d, int n)
{
    int i = blockIdx.x * 256 + threadIdx.x;
    if (i < n) d[i] = f2bf(s[i]);
}

// ---------------- concat per-layer QKV bias: [bq;bk;bv] -> (NLAY,1536) ----------------
__global__ __launch_bounds__(256)
void concat_bias_kernel(const float* __restrict__ bq, const float* __restrict__ bk,
                        const float* __restrict__ bv, float* __restrict__ dst)
{
    int i = blockIdx.x * 256 + threadIdx.x;
    if (i >= NLAY * QKVW) return;
    int l = i / QKVW, j = i - l * QKVW;
    float v = (j < WDIM) ? bq[l * WDIM + j]
            : (j < 2 * WDIM) ? bk[l * WDIM + j - WDIM]
            : bv[l * WDIM + j - 2 * WDIM];
    dst[i] = v;
}

// ---------------- tiled transpose + convert: src (K,N) -> dst (N,K) bf16 ----------------
template<typename T>
__global__ __launch_bounds__(256)
void transpose_cvt_kernel(const T* __restrict__ src, int lds_, long ssn, long ssh,
                          u16* __restrict__ dst, int ldd, long dsn, long dsh,
                          int HH)
{
    int z = blockIdx.z;
    int zn = z / HH, zh = z - zn * HH;
    src += (long)zn * ssn + (long)zh * ssh;
    dst += (long)zn * dsn + (long)zh * dsh;
    __shared__ T tile[32][33];
    int n0 = blockIdx.x * 32, k0 = blockIdx.y * 32;
    int tx = threadIdx.x & 31, ty = threadIdx.x >> 5;  // 32 x 8
    #pragma unroll
    for (int i = 0; i < 32; i += 8)
        tile[ty + i][tx] = src[(long)(k0 + ty + i) * lds_ + n0 + tx];
    __syncthreads();
    #pragma unroll
    for (int i = 0; i < 32; i += 8)
        dst[(long)(n0 + ty + i) * ldd + k0 + tx] = to_bf(tile[tx][ty + i]);
}

// ---------------- embed + positional encoding ----------------
__global__ __launch_bounds__(128)
void embed_kernel(const int* __restrict__ captions, const float* __restrict__ emb,
                  const float* __restrict__ pe, float* __restrict__ x, u16* __restrict__ xb)
{
    int r = blockIdx.x;            // 0..NT-1
    int t = r % TLEN;
    int cap = captions[r];
    const float4* e4 = (const float4*)(emb + (long)cap * WDIM);
    const float4* p4 = (const float4*)(pe + (long)t * WDIM);
    float4 a = e4[threadIdx.x], b = p4[threadIdx.x];
    float4 o = make_float4(a.x + b.x, a.y + b.y, a.z + b.z, a.w + b.w);
    ((float4*)(x + (long)r * WDIM))[threadIdx.x] = o;
    ushort4 ob = make_ushort4(f2bf(o.x), f2bf(o.y), f2bf(o.z), f2bf(o.w));
    ((ushort4*)(xb + (long)r * WDIM))[threadIdx.x] = ob;
}

// ---------------- bf16 MFMA GEMM (m97 structure + XCD-chunked swizzle) ----------------
// C[z] = act(alpha * A[z] @ B[z]^T + bias); A (M,K) bf16 row-major,
// B stored TRANSPOSED (N,K) bf16 row-major. C f32 and/or Cb bf16 outputs.
// NTST: non-temporal C stores (huge write-once outputs; bypass L2 so the
// write stream doesn't evict the A/B panels being reused).
#define GBM 128
#define GBN 128
#define GBK 32

template<int RELU, int NTST>
__global__ __launch_bounds__(256)
void mfma_gemm_kernel(const u16* __restrict__ A, int lda, long sAn, long sAh,
                      const u16* __restrict__ B, int ldb, long sBn, long sBh,
                      float* __restrict__ C, u16* __restrict__ Cb, int ldc, long sCn, long sCh,
                      const float* __restrict__ bias,
                      int M, int N, int K, int HH, float alpha)
{
    int z = blockIdx.z;
    int zn = z / HH, zh = z - zn * HH;
    A += (long)zn * sAn + (long)zh * sAh;
    B += (long)zn * sBn + (long)zh * sBh;
    long coff = (long)zn * sCn + (long)zh * sCh;

    // XCD-chunked bijective swizzle (m204): all M-blocks sharing one B panel
    // land consecutively on ONE XCD -> B-panel L2 reuse.
    int nwg  = gridDim.x * gridDim.y;
    int orig = blockIdx.y * gridDim.x + blockIdx.x;
    int q = nwg >> 3, r = nwg & 7, xcd = orig & 7, rest = orig >> 3;
    int nw = (xcd < r ? xcd * (q + 1) : r * (q + 1) + (xcd - r) * q) + rest;
    int bx = nw / gridDim.y, by = nw - bx * gridDim.y;
    int bm = by * GBM, bn = bx * GBN;

    __shared__ u16 As[GBM * GBK];   // [row][k] linear, k contiguous
    __shared__ u16 Bs[GBN * GBK];   // [col][k] linear

    int tid = threadIdx.x;
    int w = tid >> 6, lane = tid & 63;
    int wr = w >> 1, wc = w & 1;         // 2x2 wave grid, 64x64 per wave
    int lrow = lane & 15, kgrp = lane >> 4;

    f32x4 acc[4][4] = {};

    for (int k0 = 0; k0 < K; k0 += GBK) {
        #pragma unroll
        for (int i = 0; i < 2; i++) {
            int c = tid + i * 256;
            int row = c >> 2, ko = (c & 3) << 3;
            int gr = bm + row; if (gr >= M) gr = M - 1;   // clamp (ragged M=8 case)
            const u16* src = A + (long)gr * lda + k0 + ko;
            u16* dst = &As[(size_t)(w * 64 + i * 256) * 8];   // wave-uniform base
            __builtin_amdgcn_global_load_lds((const __attribute__((address_space(1))) void*)src,
                                             (__attribute__((address_space(3))) void*)dst, 16, 0, 0);
        }
        #pragma unroll
        for (int i = 0; i < 2; i++) {
            int c = tid + i * 256;
            int row = c >> 2, ko = (c & 3) << 3;
            const u16* src = B + (long)(bn + row) * ldb + k0 + ko;
            u16* dst = &Bs[(size_t)(w * 64 + i * 256) * 8];
            __builtin_amdgcn_global_load_lds((const __attribute__((address_space(1))) void*)src,
                                             (__attribute__((address_space(3))) void*)dst, 16, 0, 0);
        }
        __syncthreads();
        bf16x8 av[4], bv[4];
        #pragma unroll
        for (int m = 0; m < 4; m++)
            av[m] = *(const bf16x8*)&As[(wr * 64 + m * 16 + lrow) * GBK + kgrp * 8];
        #pragma unroll
        for (int n = 0; n < 4; n++)
            bv[n] = *(const bf16x8*)&Bs[(wc * 64 + n * 16 + lrow) * GBK + kgrp * 8];
        #pragma unroll
        for (int m = 0; m < 4; m++)
            #pragma unroll
            for (int n = 0; n < 4; n++)
                acc[m][n] = __builtin_amdgcn_mfma_f32_16x16x32_bf16(av[m], bv[n], acc[m][n], 0, 0, 0);
        __syncthreads();
    }

    if (C)  C  += coff;
    if (Cb) Cb += coff;
    // C/D layout: col = lane&15, row = (lane>>4)*4 + reg   [m89/m91 verified]
    #pragma unroll
    for (int m = 0; m < 4; m++) {
        int rb = bm + wr * 64 + m * 16 + kgrp * 4;
        #pragma unroll
        for (int n = 0; n < 4; n++) {
            int gc = bn + wc * 64 + n * 16 + lrow;
            float bvv = bias ? bias[gc] : 0.f;
            #pragma unroll
            for (int r2 = 0; r2 < 4; r2++) {
                int gr = rb + r2;
                if (gr < M) {
                    float v2 = acc[m][n][r2] * alpha + bvv;
                    if (RELU) v2 = fmaxf(v2, 0.f);
                    if (C) {
                        if (NTST) __builtin_nontemporal_store(v2, &C[(long)gr * ldc + gc]);
                        else      C[(long)gr * ldc + gc] = v2;
                    }
                    if (Cb) Cb[(long)gr * ldc + gc] = f2bf(v2);
                }
            }
        }
    }
}

// ---------------- causal softmax: f32 scores -> bf16 P ----------------
__global__ __launch_bounds__(256)
void softmax_causal_kernel(const float* __restrict__ scores, u16* __restrict__ pb)
{
    long row = blockIdx.x;                 // n*H*T + h*T + s
    int s = (int)(row % TLEN);
    const float* p = scores + row * TLEN;
    u16* o = pb + row * TLEN;
    int tid = threadIdx.x;
    float v0 = p[tid], v1 = p[tid + 256];
    bool m0 = (tid <= s), m1 = (tid + 256 <= s);
    __shared__ float red[256];
    float mx = fmaxf(m0 ? v0 : -INFINITY, m1 ? v1 : -INFINITY);
    red[tid] = mx; __syncthreads();
    for (int off = 128; off > 0; off >>= 1) {
        if (tid < off) red[tid] = fmaxf(red[tid], red[tid + off]);
        __syncthreads();
    }
    mx = red[0]; __syncthreads();
    float e0 = m0 ? expf(v0 - mx) : 0.f;
    float e1 = m1 ? expf(v1 - mx) : 0.f;
    red[tid] = e0 + e1; __syncthreads();
    for (int off = 128; off > 0; off >>= 1) {
        if (tid < off) red[tid] += red[tid + off];
        __syncthreads();
    }
    float inv = 1.f / red[0];
    o[tid]       = f2bf(e0 * inv);
    o[tid + 256] = f2bf(e1 * inv);
}

// ---------------- x = LayerNorm(x + t2); writes f32 x and bf16 xb ----------------
__global__ __launch_bounds__(256)
void add_ln_kernel(float* __restrict__ x, u16* __restrict__ xb,
                   const float* __restrict__ t2, long t2div,
                   const float* __restrict__ w, const float* __restrict__ b)
{
    long r = blockIdx.x;
    float* xr = x + r * WDIM;
    u16* xbr = xb + r * WDIM;
    const float* tr = t2 + (r / t2div) * WDIM;
    int tid = threadIdx.x;
    float v0 = xr[tid] + tr[tid];
    float v1 = xr[tid + 256] + tr[tid + 256];
    __shared__ float red[256];
    red[tid] = v0 + v1; __syncthreads();
    for (int off = 128; off > 0; off >>= 1) {
        if (tid < off) red[tid] += red[tid + off];
        __syncthreads();
    }
    float mean = red[0] * (1.f / WDIM); __syncthreads();
    float d0 = v0 - mean, d1 = v1 - mean;
    red[tid] = d0 * d0 + d1 * d1; __syncthreads();
    for (int off = 128; off > 0; off >>= 1) {
        if (tid < off) red[tid] += red[tid + off];
        __syncthreads();
    }
    float rstd = 1.f / sqrtf(red[0] * (1.f / WDIM) + 1e-5f);
    float o0 = d0 * rstd * w[tid] + b[tid];
    float o1 = d1 * rstd * w[tid + 256] + b[tid + 256];
    xr[tid] = o0;        xr[tid + 256] = o1;
    xbr[tid] = f2bf(o0); xbr[tid + 256] = f2bf(o1);
}

extern "C" void kernel_launch(void* const* d_in, const int* in_sizes, int n_in,
                              void* d_out, int out_size, void* d_ws, size_t ws_size,
                              hipStream_t stream)
{
    const float* features = (const float*)d_in[0];
    const int*   captions = (const int*)  d_in[1];
    const float* emb      = (const float*)d_in[2];
    const float* pe       = (const float*)d_in[3];
    const float* vis_w    = (const float*)d_in[4];
    const float* vis_b    = (const float*)d_in[5];
    const float* sa_wq    = (const float*)d_in[6];
    const float* sa_bq    = (const float*)d_in[7];
    const float* sa_wk    = (const float*)d_in[8];
    const float* sa_bk    = (const float*)d_in[9];
    const float* sa_wv    = (const float*)d_in[10];
    const float* sa_bv    = (const float*)d_in[11];
    const float* sa_wo    = (const float*)d_in[12];
    const float* sa_bo    = (const float*)d_in[13];
    // ca_wq/bq/wk/bk (14..17) unused: len-1 memory => softmax == 1 identically
    const float* ca_wv    = (const float*)d_in[18];
    const float* ca_bv    = (const float*)d_in[19];
    const float* ca_wo    = (const float*)d_in[20];
    const float* ca_bo    = (const float*)d_in[21];
    const float* ff1_w    = (const float*)d_in[22];
    const float* ff1_b    = (const float*)d_in[23];
    const float* ff2_w    = (const float*)d_in[24];
    const float* ff2_b    = (const float*)d_in[25];
    const float* ln1_w    = (const float*)d_in[26];
    const float* ln1_b    = (const float*)d_in[27];
    const float* ln2_w    = (const float*)d_in[28];
    const float* ln2_b    = (const float*)d_in[29];
    const float* ln3_w    = (const float*)d_in[30];
    const float* ln3_b    = (const float*)d_in[31];
    const float* out_w    = (const float*)d_in[32];
    const float* out_b    = (const float*)d_in[33];

    // ---- workspace carve ----
    char* p = (char*)d_ws;
    auto alloc = [&](size_t bytes) { char* r = p; p += (bytes + 255) & ~(size_t)255; return r; };
    float* x    = (float*)alloc((size_t)NT * WDIM * 4);
    float* t2   = (float*)alloc((size_t)NT * WDIM * 4);
    float* memb = (float*)alloc((size_t)NBATCH * WDIM * 4);
    float* cav  = (float*)alloc((size_t)NBATCH * WDIM * 4);
    // union region: scores f32 (SA phase) | yb bf16 (PV->Oproj) | hb bf16 (FFN)
    char*  reg1 = alloc((size_t)NBATCH * NHEADS * TLEN * TLEN * 4);
    float* scores = (float*)reg1;
    u16*   yb     = (u16*)reg1;
    u16*   hb     = (u16*)reg1;
    u16* xb    = (u16*)alloc((size_t)NT * WDIM * 2);
    u16* qkvb  = (u16*)alloc((size_t)NT * QKVW * 2);
    u16* vtb   = (u16*)alloc((size_t)NT * WDIM * 2);
    u16* pb    = (u16*)alloc((size_t)NBATCH * NHEADS * TLEN * TLEN * 2);
    u16* featb = (u16*)alloc((size_t)NBATCH * DFEAT * 2);
    u16* membf = (u16*)alloc((size_t)NBATCH * WDIM * 2);
    u16* cvb   = (u16*)alloc((size_t)NBATCH * WDIM * 2);
    float* qkv_bias = (float*)alloc((size_t)NLAY * QKVW * 4);
    u16* vis_wT = (u16*)alloc((size_t)WDIM * DFEAT * 2);
    u16* qkvT   = (u16*)alloc((size_t)NLAY * QKVW * WDIM * 2);
    u16* sa_woT = (u16*)alloc((size_t)NLAY * WDIM * WDIM * 2);
    u16* ca_wvT = (u16*)alloc((size_t)NLAY * WDIM * WDIM * 2);
    u16* ca_woT = (u16*)alloc((size_t)NLAY * WDIM * WDIM * 2);
    u16* ff1T   = (u16*)alloc((size_t)NLAY * WDIM * FFDIM * 2);
    u16* ff2T   = (u16*)alloc((size_t)NLAY * FFDIM * WDIM * 2);
    u16* out_wT = (u16*)alloc((size_t)WDIM * VOCAB * 2);

    auto gemm = [&](const u16* A, int lda, long sAn, long sAh,
                    const u16* B, int ldb, long sBn, long sBh,
                    float* C, u16* Cb, int ldc, long sCn, long sCh,
                    const float* bias, int M, int N, int K, int HH, int batch,
                    float alpha, bool relu, bool nt)
    {
        dim3 g(N / GBN, (M + GBM - 1) / GBM, batch), blk(256);
        if (nt)
            mfma_gemm_kernel<0, 1><<<g, blk, 0, stream>>>(A, lda, sAn, sAh, B, ldb, sBn, sBh,
                                                          C, Cb, ldc, sCn, sCh, bias, M, N, K, HH, alpha);
        else if (relu)
            mfma_gemm_kernel<1, 0><<<g, blk, 0, stream>>>(A, lda, sAn, sAh, B, ldb, sBn, sBh,
                                                          C, Cb, ldc, sCn, sCh, bias, M, N, K, HH, alpha);
        else
            mfma_gemm_kernel<0, 0><<<g, blk, 0, stream>>>(A, lda, sAn, sAh, B, ldb, sBn, sBh,
                                                          C, Cb, ldc, sCn, sCh, bias, M, N, K, HH, alpha);
    };
    auto transposeF = [&](const float* src, int lds_, long ssn, long ssh,
                          u16* dst, int ldd, long dsn, long dsh,
                          int K, int N, int batch, int HH)
    {
        dim3 g(N / 32, K / 32, batch), blk(256);
        transpose_cvt_kernel<float><<<g, blk, 0, stream>>>(src, lds_, ssn, ssh, dst, ldd, dsn, dsh, HH);
    };
    auto transposeB = [&](const u16* src, int lds_, long ssn, long ssh,
                          u16* dst, int ldd, long dsn, long dsh,
                          int K, int N, int batch, int HH)
    {
        dim3 g(N / 32, K / 32, batch), blk(256);
        transpose_cvt_kernel<u16><<<g, blk, 0, stream>>>(src, lds_, ssn, ssh, dst, ldd, dsn, dsh, HH);
    };

    // ---- weight conversion (per call; deterministic) ----
    cvt_kernel<<<(NBATCH * DFEAT + 255) / 256, 256, 0, stream>>>(features, featb, NBATCH * DFEAT);
    concat_bias_kernel<<<(NLAY * QKVW + 255) / 256, 256, 0, stream>>>(sa_bq, sa_bk, sa_bv, qkv_bias);
    transposeF(vis_w, WDIM, 0, 0, vis_wT, DFEAT, 0, 0, DFEAT, WDIM, 1, 1);
    transposeF(sa_wq, WDIM, (long)WDIM * WDIM, 0, qkvT,                WDIM, (long)QKVW * WDIM, 0, WDIM, WDIM, NLAY, 1);
    transposeF(sa_wk, WDIM, (long)WDIM * WDIM, 0, qkvT + (long)WDIM * WDIM,     WDIM, (long)QKVW * WDIM, 0, WDIM, WDIM, NLAY, 1);
    transposeF(sa_wv, WDIM, (long)WDIM * WDIM, 0, qkvT + (long)2 * WDIM * WDIM, WDIM, (long)QKVW * WDIM, 0, WDIM, WDIM, NLAY, 1);
    transposeF(sa_wo, WDIM, (long)WDIM * WDIM, 0, sa_woT, WDIM, (long)WDIM * WDIM, 0, WDIM, WDIM, NLAY, 1);
    transposeF(ca_wv, WDIM, (long)WDIM * WDIM, 0, ca_wvT, WDIM, (long)WDIM * WDIM, 0, WDIM, WDIM, NLAY, 1);
    transposeF(ca_wo, WDIM, (long)WDIM * WDIM, 0, ca_woT, WDIM, (long)WDIM * WDIM, 0, WDIM, WDIM, NLAY, 1);
    transposeF(ff1_w, FFDIM, (long)WDIM * FFDIM, 0, ff1T, WDIM, (long)FFDIM * WDIM, 0, WDIM, FFDIM, NLAY, 1);
    transposeF(ff2_w, WDIM, (long)FFDIM * WDIM, 0, ff2T, FFDIM, (long)WDIM * FFDIM, 0, FFDIM, WDIM, NLAY, 1);
    transposeF(out_w, VOCAB, 0, 0, out_wT, WDIM, 0, 0, WDIM, VOCAB, 1, 1);

    // memory = features @ vis_w + vis_b   (8 x 512), keep f32 + bf16
    gemm(featb, DFEAT, 0, 0, vis_wT, DFEAT, 0, 0, memb, membf, WDIM, 0, 0,
         vis_b, NBATCH, WDIM, DFEAT, 1, 1, 1.f, false, false);
    // x = emb[captions] + pe
    embed_kernel<<<NT, 128, 0, stream>>>(captions, emb, pe, x, xb);

    const float iscale = 1.f / sqrtf((float)DHEAD);
    const long TQ = (long)TLEN * QKVW;
    const long TW = (long)TLEN * WDIM;
    const long TT = (long)TLEN * TLEN;
    for (int l = 0; l < NLAY; l++) {
        long wo  = (long)l * WDIM * WDIM;
        long bo_ = (long)l * WDIM;
        // ---- self-attention: fused QKV projection (N=1536) ----
        gemm(xb, WDIM, 0, 0, qkvT + (long)l * QKVW * WDIM, WDIM, 0, 0,
             nullptr, qkvb, QKVW, 0, 0, qkv_bias + (long)l * QKVW,
             NT, QKVW, WDIM, 1, 1, 1.f, false, false);
        // V^T per (n,h): qkvb[n*T+t][1024 + h*128 + d] -> vtb [n][h][d][t]
        transposeB(qkvb + 2 * WDIM, QKVW, TQ, DHEAD,
                   vtb, TLEN, (long)NHEADS * DHEAD * TLEN, (long)DHEAD * TLEN,
                   TLEN, DHEAD, NBATCH * NHEADS, NHEADS);
        // scores = (Q_h @ K_h^T) * iscale
        gemm(qkvb, QKVW, TQ, DHEAD, qkvb + WDIM, QKVW, TQ, DHEAD,
             scores, nullptr, TLEN, (long)NHEADS * TT, TT,
             nullptr, TLEN, TLEN, DHEAD, NHEADS, NBATCH * NHEADS, iscale, false, false);
        softmax_causal_kernel<<<NBATCH * NHEADS * TLEN, 256, 0, stream>>>(scores, pb);
        // y = P @ V_h  (B = V^T tile, (N=d, K=t))
        gemm(pb, TLEN, (long)NHEADS * TT, TT,
             vtb, TLEN, (long)NHEADS * DHEAD * TLEN, (long)DHEAD * TLEN,
             nullptr, yb, WDIM, TW, DHEAD,
             nullptr, TLEN, DHEAD, TLEN, NHEADS, NBATCH * NHEADS, 1.f, false, false);
        // t2 = y @ wo + bo
        gemm(yb, WDIM, 0, 0, sa_woT + wo, WDIM, 0, 0, t2, nullptr, WDIM, 0, 0,
             sa_bo + bo_, NT, WDIM, WDIM, 1, 1, 1.f, false, false);
        add_ln_kernel<<<NT, 256, 0, stream>>>(x, xb, t2, 1, ln1_w + bo_, ln1_b + bo_);
        // ---- cross-attention (collapsed: softmax over len-1 == 1) ----
        gemm(membf, WDIM, 0, 0, ca_wvT + wo, WDIM, 0, 0, nullptr, cvb, WDIM, 0, 0,
             ca_bv + bo_, NBATCH, WDIM, WDIM, 1, 1, 1.f, false, false);
        gemm(cvb, WDIM, 0, 0, ca_woT + wo, WDIM, 0, 0, cav, nullptr, WDIM, 0, 0,
             ca_bo + bo_, NBATCH, WDIM, WDIM, 1, 1, 1.f, false, false);
        add_ln_kernel<<<NT, 256, 0, stream>>>(x, xb, cav, TLEN, ln2_w + bo_, ln2_b + bo_);
        // ---- FFN ----
        gemm(xb, WDIM, 0, 0, ff1T + (long)l * FFDIM * WDIM, WDIM, 0, 0,
             nullptr, hb, FFDIM, 0, 0, ff1_b + (long)l * FFDIM,
             NT, FFDIM, WDIM, 1, 1, 1.f, true, false);
        gemm(hb, FFDIM, 0, 0, ff2T + (long)l * WDIM * FFDIM, FFDIM, 0, 0,
             t2, nullptr, WDIM, 0, 0, ff2_b + bo_, NT, WDIM, FFDIM, 1, 1, 1.f, false, false);
        add_ln_kernel<<<NT, 256, 0, stream>>>(x, xb, t2, 1, ln3_w + bo_, ln3_b + bo_);
    }
    // out = x @ out_w + out_b   (4096 x 32000) — non-temporal f32 stores
    gemm(xb, WDIM, 0, 0, out_wT, WDIM, 0, 0, (float*)d_out, nullptr, VOCAB, 0, 0,
         out_b, NT, VOCAB, WDIM, 1, 1, 1.f, false, true);
}

// Round 6
// 823.375 us; speedup vs baseline: 4.8546x; 1.0551x over previous
//
#include <hip/hip_runtime.h>
#include <math.h>

#define WDIM   512
#define TLEN   512
#define NBATCH 8
#define NHEADS 4
#define DHEAD  128
#define VOCAB  32000
#define NLAY   2
#define FFDIM  2048
#define DFEAT  1024
#define NT     (NBATCH * TLEN)   // 4096 rows
#define QKVW   (3 * WDIM)        // 1536

typedef unsigned short u16;
typedef __attribute__((ext_vector_type(8))) short bf16x8;
typedef __attribute__((ext_vector_type(4))) float f32x4;

__device__ inline u16 f2bf(float f) {
    union { float f; unsigned u; } v; v.f = f;
    unsigned r = v.u + 0x7fffu + ((v.u >> 16) & 1u);
    return (u16)(r >> 16);
}
__device__ inline u16 to_bf(float f) { return f2bf(f); }
__device__ inline u16 to_bf(u16 v)  { return v; }

// ---------------- f32 -> bf16 flat convert ----------------
__global__ __launch_bounds__(256)
void cvt_kernel(const float* __restrict__ s, u16* __restrict__ d, int n)
{
    int i = blockIdx.x * 256 + threadIdx.x;
    if (i < n) d[i] = f2bf(s[i]);
}

// ---------------- concat per-layer QKV bias: [bq;bk;bv] -> (NLAY,1536) ----------------
__global__ __launch_bounds__(256)
void concat_bias_kernel(const float* __restrict__ bq, const float* __restrict__ bk,
                        const float* __restrict__ bv, float* __restrict__ dst)
{
    int i = blockIdx.x * 256 + threadIdx.x;
    if (i >= NLAY * QKVW) return;
    int l = i / QKVW, j = i - l * QKVW;
    float v = (j < WDIM) ? bq[l * WDIM + j]
            : (j < 2 * WDIM) ? bk[l * WDIM + j - WDIM]
            : bv[l * WDIM + j - 2 * WDIM];
    dst[i] = v;
}

// ---------------- tiled transpose + convert: src (K,N) -> dst (N,K) bf16 ----------------
template<typename T>
__global__ __launch_bounds__(256)
void transpose_cvt_kernel(const T* __restrict__ src, int lds_, long ssn, long ssh,
                          u16* __restrict__ dst, int ldd, long dsn, long dsh,
                          int HH)
{
    int z = blockIdx.z;
    int zn = z / HH, zh = z - zn * HH;
    src += (long)zn * ssn + (long)zh * ssh;
    dst += (long)zn * dsn + (long)zh * dsh;
    __shared__ T tile[32][33];
    int n0 = blockIdx.x * 32, k0 = blockIdx.y * 32;
    int tx = threadIdx.x & 31, ty = threadIdx.x >> 5;  // 32 x 8
    #pragma unroll
    for (int i = 0; i < 32; i += 8)
        tile[ty + i][tx] = src[(long)(k0 + ty + i) * lds_ + n0 + tx];
    __syncthreads();
    #pragma unroll
    for (int i = 0; i < 32; i += 8)
        dst[(long)(n0 + ty + i) * ldd + k0 + tx] = to_bf(tile[tx][ty + i]);
}

// ---------------- embed + positional encoding ----------------
__global__ __launch_bounds__(128)
void embed_kernel(const int* __restrict__ captions, const float* __restrict__ emb,
                  const float* __restrict__ pe, float* __restrict__ x, u16* __restrict__ xb)
{
    int r = blockIdx.x;            // 0..NT-1
    int t = r % TLEN;
    int cap = captions[r];
    const float4* e4 = (const float4*)(emb + (long)cap * WDIM);
    const float4* p4 = (const float4*)(pe + (long)t * WDIM);
    float4 a = e4[threadIdx.x], b = p4[threadIdx.x];
    float4 o = make_float4(a.x + b.x, a.y + b.y, a.z + b.z, a.w + b.w);
    ((float4*)(x + (long)r * WDIM))[threadIdx.x] = o;
    ushort4 ob = make_ushort4(f2bf(o.x), f2bf(o.y), f2bf(o.z), f2bf(o.w));
    ((ushort4*)(xb + (long)r * WDIM))[threadIdx.x] = ob;
}

// ---------------- bf16 MFMA GEMM (m97 structure + XCD-chunked swizzle) ----------------
// C[z] = act(alpha * A[z] @ B[z]^T + bias); A (M,K) bf16 row-major,
// B stored TRANSPOSED (N,K) bf16 row-major. C f32 and/or Cb bf16 outputs.
// NTST: non-temporal, LDS-staged fully-coalesced f32x4 C stores (write-once
//       huge outputs; full 128B lines -> no RMW, no L2 thrash).
// CAUSAL: skip tiles fully above the diagonal (bn >= bm+GBM).
#define GBM 128
#define GBN 128
#define GBK 32

template<int RELU, int NTST, int CAUSAL>
__global__ __launch_bounds__(256)
void mfma_gemm_kernel(const u16* __restrict__ A, int lda, long sAn, long sAh,
                      const u16* __restrict__ B, int ldb, long sBn, long sBh,
                      float* __restrict__ C, u16* __restrict__ Cb, int ldc, long sCn, long sCh,
                      const float* __restrict__ bias,
                      int M, int N, int K, int HH, float alpha)
{
    int z = blockIdx.z;
    int zn = z / HH, zh = z - zn * HH;
    A += (long)zn * sAn + (long)zh * sAh;
    B += (long)zn * sBn + (long)zh * sBh;
    long coff = (long)zn * sCn + (long)zh * sCh;

    // XCD-chunked bijective swizzle (m204): all M-blocks sharing one B panel
    // land consecutively on ONE XCD -> B-panel L2 reuse.
    int nwg  = gridDim.x * gridDim.y;
    int orig = blockIdx.y * gridDim.x + blockIdx.x;
    int q = nwg >> 3, r = nwg & 7, xcd = orig & 7, rest = orig >> 3;
    int nw = (xcd < r ? xcd * (q + 1) : r * (q + 1) + (xcd - r) * q) + rest;
    int bx = nw / gridDim.y, by = nw - bx * gridDim.y;
    int bm = by * GBM, bn = bx * GBN;

    if (CAUSAL && bn >= bm + GBM) return;   // fully-masked tile (softmax zeroes it)

    __shared__ u16 smem[2 * GBM * GBK];     // As | Bs ; reused as f32[32][128] epilogue buf
    u16* As = smem;
    u16* Bs = smem + GBM * GBK;

    int tid = threadIdx.x;
    int w = tid >> 6, lane = tid & 63;
    int wr = w >> 1, wc = w & 1;         // 2x2 wave grid, 64x64 per wave
    int lrow = lane & 15, kgrp = lane >> 4;

    f32x4 acc[4][4] = {};

    for (int k0 = 0; k0 < K; k0 += GBK) {
        #pragma unroll
        for (int i = 0; i < 2; i++) {
            int c = tid + i * 256;
            int row = c >> 2, ko = (c & 3) << 3;
            int gr = bm + row; if (gr >= M) gr = M - 1;   // clamp (ragged M=8 case)
            const u16* src = A + (long)gr * lda + k0 + ko;
            u16* dst = &As[(size_t)(w * 64 + i * 256) * 8];   // wave-uniform base
            __builtin_amdgcn_global_load_lds((const __attribute__((address_space(1))) void*)src,
                                             (__attribute__((address_space(3))) void*)dst, 16, 0, 0);
        }
        #pragma unroll
        for (int i = 0; i < 2; i++) {
            int c = tid + i * 256;
            int row = c >> 2, ko = (c & 3) << 3;
            const u16* src = B + (long)(bn + row) * ldb + k0 + ko;
            u16* dst = &Bs[(size_t)(w * 64 + i * 256) * 8];
            __builtin_amdgcn_global_load_lds((const __attribute__((address_space(1))) void*)src,
                                             (__attribute__((address_space(3))) void*)dst, 16, 0, 0);
        }
        __syncthreads();
        bf16x8 av[4], bv[4];
        #pragma unroll
        for (int m = 0; m < 4; m++)
            av[m] = *(const bf16x8*)&As[(wr * 64 + m * 16 + lrow) * GBK + kgrp * 8];
        #pragma unroll
        for (int n = 0; n < 4; n++)
            bv[n] = *(const bf16x8*)&Bs[(wc * 64 + n * 16 + lrow) * GBK + kgrp * 8];
        #pragma unroll
        for (int m = 0; m < 4; m++)
            #pragma unroll
            for (int n = 0; n < 4; n++)
                acc[m][n] = __builtin_amdgcn_mfma_f32_16x16x32_bf16(av[m], bv[n], acc[m][n], 0, 0, 0);
        __syncthreads();
    }

    // C/D layout: col = lane&15, row = (lane>>4)*4 + reg   [m89/m91 verified]
    if (NTST) {
        // LDS-staged coalesced NT epilogue: 4 passes of 32 rows x 128 cols f32.
        float* ls = (float*)smem;     // 32*128 f32 = 16 KB
        C += coff;
        #pragma unroll
        for (int pass = 0; pass < 4; pass++) {
            if (wr == (pass >> 1)) {
                #pragma unroll
                for (int m2 = 0; m2 < 2; m2++) {
                    int m = (pass & 1) * 2 + m2;
                    #pragma unroll
                    for (int n = 0; n < 4; n++) {
                        int gc = wc * 64 + n * 16 + lrow;
                        float bvv = bias ? bias[bn + gc] : 0.f;
                        #pragma unroll
                        for (int r2 = 0; r2 < 4; r2++) {
                            float v2 = acc[m][n][r2] * alpha + bvv;
                            if (RELU) v2 = fmaxf(v2, 0.f);
                            ls[(m2 * 16 + kgrp * 4 + r2) * 128 + gc] = v2;
                        }
                    }
                }
            }
            __syncthreads();
            #pragma unroll
            for (int i = 0; i < 4; i++) {
                int j = tid + i * 256;            // 0..1023 f32x4
                int row = j >> 5, cg = j & 31;
                int gr = bm + pass * 32 + row;
                if (gr < M) {
                    f32x4 v4 = *(const f32x4*)&ls[row * 128 + cg * 4];
                    __builtin_nontemporal_store(v4, (f32x4*)&C[(long)gr * ldc + bn + cg * 4]);
                }
            }
            __syncthreads();
        }
        return;
    }

    if (C)  C  += coff;
    if (Cb) Cb += coff;
    #pragma unroll
    for (int m = 0; m < 4; m++) {
        int rb = bm + wr * 64 + m * 16 + kgrp * 4;
        #pragma unroll
        for (int n = 0; n < 4; n++) {
            int gc = bn + wc * 64 + n * 16 + lrow;
            float bvv = bias ? bias[gc] : 0.f;
            #pragma unroll
            for (int r2 = 0; r2 < 4; r2++) {
                int gr = rb + r2;
                if (gr < M) {
                    float v2 = acc[m][n][r2] * alpha + bvv;
                    if (RELU) v2 = fmaxf(v2, 0.f);
                    if (C)  C[(long)gr * ldc + gc]  = v2;
                    if (Cb) Cb[(long)gr * ldc + gc] = f2bf(v2);
                }
            }
        }
    }
}

// ---------------- causal softmax: f32 scores -> bf16 P ----------------
__global__ __launch_bounds__(256)
void softmax_causal_kernel(const float* __restrict__ scores, u16* __restrict__ pb)
{
    long row = blockIdx.x;                 // n*H*T + h*T + s
    int s = (int)(row % TLEN);
    const float* p = scores + row * TLEN;
    u16* o = pb + row * TLEN;
    int tid = threadIdx.x;
    float v0 = p[tid], v1 = p[tid + 256];
    bool m0 = (tid <= s), m1 = (tid + 256 <= s);
    __shared__ float red[256];
    float mx = fmaxf(m0 ? v0 : -INFINITY, m1 ? v1 : -INFINITY);
    red[tid] = mx; __syncthreads();
    for (int off = 128; off > 0; off >>= 1) {
        if (tid < off) red[tid] = fmaxf(red[tid], red[tid + off]);
        __syncthreads();
    }
    mx = red[0]; __syncthreads();
    float e0 = m0 ? expf(v0 - mx) : 0.f;
    float e1 = m1 ? expf(v1 - mx) : 0.f;
    red[tid] = e0 + e1; __syncthreads();
    for (int off = 128; off > 0; off >>= 1) {
        if (tid < off) red[tid] += red[tid + off];
        __syncthreads();
    }
    float inv = 1.f / red[0];
    o[tid]       = f2bf(e0 * inv);
    o[tid + 256] = f2bf(e1 * inv);
}

// ---------------- x = LayerNorm(x + t2); writes f32 x and bf16 xb ----------------
__global__ __launch_bounds__(256)
void add_ln_kernel(float* __restrict__ x, u16* __restrict__ xb,
                   const float* __restrict__ t2, long t2div,
                   const float* __restrict__ w, const float* __restrict__ b)
{
    long r = blockIdx.x;
    float* xr = x + r * WDIM;
    u16* xbr = xb + r * WDIM;
    const float* tr = t2 + (r / t2div) * WDIM;
    int tid = threadIdx.x;
    float v0 = xr[tid] + tr[tid];
    float v1 = xr[tid + 256] + tr[tid + 256];
    __shared__ float red[256];
    red[tid] = v0 + v1; __syncthreads();
    for (int off = 128; off > 0; off >>= 1) {
        if (tid < off) red[tid] += red[tid + off];
        __syncthreads();
    }
    float mean = red[0] * (1.f / WDIM); __syncthreads();
    float d0 = v0 - mean, d1 = v1 - mean;
    red[tid] = d0 * d0 + d1 * d1; __syncthreads();
    for (int off = 128; off > 0; off >>= 1) {
        if (tid < off) red[tid] += red[tid + off];
        __syncthreads();
    }
    float rstd = 1.f / sqrtf(red[0] * (1.f / WDIM) + 1e-5f);
    float o0 = d0 * rstd * w[tid] + b[tid];
    float o1 = d1 * rstd * w[tid + 256] + b[tid + 256];
    xr[tid] = o0;        xr[tid + 256] = o1;
    xbr[tid] = f2bf(o0); xbr[tid + 256] = f2bf(o1);
}

extern "C" void kernel_launch(void* const* d_in, const int* in_sizes, int n_in,
                              void* d_out, int out_size, void* d_ws, size_t ws_size,
                              hipStream_t stream)
{
    const float* features = (const float*)d_in[0];
    const int*   captions = (const int*)  d_in[1];
    const float* emb      = (const float*)d_in[2];
    const float* pe       = (const float*)d_in[3];
    const float* vis_w    = (const float*)d_in[4];
    const float* vis_b    = (const float*)d_in[5];
    const float* sa_wq    = (const float*)d_in[6];
    const float* sa_bq    = (const float*)d_in[7];
    const float* sa_wk    = (const float*)d_in[8];
    const float* sa_bk    = (const float*)d_in[9];
    const float* sa_wv    = (const float*)d_in[10];
    const float* sa_bv    = (const float*)d_in[11];
    const float* sa_wo    = (const float*)d_in[12];
    const float* sa_bo    = (const float*)d_in[13];
    // ca_wq/bq/wk/bk (14..17) unused: len-1 memory => softmax == 1 identically
    const float* ca_wv    = (const float*)d_in[18];
    const float* ca_bv    = (const float*)d_in[19];
    const float* ca_wo    = (const float*)d_in[20];
    const float* ca_bo    = (const float*)d_in[21];
    const float* ff1_w    = (const float*)d_in[22];
    const float* ff1_b    = (const float*)d_in[23];
    const float* ff2_w    = (const float*)d_in[24];
    const float* ff2_b    = (const float*)d_in[25];
    const float* ln1_w    = (const float*)d_in[26];
    const float* ln1_b    = (const float*)d_in[27];
    const float* ln2_w    = (const float*)d_in[28];
    const float* ln2_b    = (const float*)d_in[29];
    const float* ln3_w    = (const float*)d_in[30];
    const float* ln3_b    = (const float*)d_in[31];
    const float* out_w    = (const float*)d_in[32];
    const float* out_b    = (const float*)d_in[33];

    // ---- workspace carve ----
    char* p = (char*)d_ws;
    auto alloc = [&](size_t bytes) { char* r = p; p += (bytes + 255) & ~(size_t)255; return r; };
    float* x    = (float*)alloc((size_t)NT * WDIM * 4);
    float* t2   = (float*)alloc((size_t)NT * WDIM * 4);
    float* memb = (float*)alloc((size_t)NBATCH * WDIM * 4);
    float* cav  = (float*)alloc((size_t)NBATCH * WDIM * 4);
    // union region: scores f32 (SA phase) | yb bf16 (PV->Oproj) | hb bf16 (FFN)
    char*  reg1 = alloc((size_t)NBATCH * NHEADS * TLEN * TLEN * 4);
    float* scores = (float*)reg1;
    u16*   yb     = (u16*)reg1;
    u16*   hb     = (u16*)reg1;
    u16* xb    = (u16*)alloc((size_t)NT * WDIM * 2);
    u16* qkvb  = (u16*)alloc((size_t)NT * QKVW * 2);
    u16* vtb   = (u16*)alloc((size_t)NT * WDIM * 2);
    u16* pb    = (u16*)alloc((size_t)NBATCH * NHEADS * TLEN * TLEN * 2);
    u16* featb = (u16*)alloc((size_t)NBATCH * DFEAT * 2);
    u16* membf = (u16*)alloc((size_t)NBATCH * WDIM * 2);
    u16* cvb   = (u16*)alloc((size_t)NBATCH * WDIM * 2);
    float* qkv_bias = (float*)alloc((size_t)NLAY * QKVW * 4);
    u16* vis_wT = (u16*)alloc((size_t)WDIM * DFEAT * 2);
    u16* qkvT   = (u16*)alloc((size_t)NLAY * QKVW * WDIM * 2);
    u16* sa_woT = (u16*)alloc((size_t)NLAY * WDIM * WDIM * 2);
    u16* ca_wvT = (u16*)alloc((size_t)NLAY * WDIM * WDIM * 2);
    u16* ca_woT = (u16*)alloc((size_t)NLAY * WDIM * WDIM * 2);
    u16* ff1T   = (u16*)alloc((size_t)NLAY * WDIM * FFDIM * 2);
    u16* ff2T   = (u16*)alloc((size_t)NLAY * FFDIM * WDIM * 2);
    u16* out_wT = (u16*)alloc((size_t)WDIM * VOCAB * 2);

    auto gemm = [&](const u16* A, int lda, long sAn, long sAh,
                    const u16* B, int ldb, long sBn, long sBh,
                    float* C, u16* Cb, int ldc, long sCn, long sCh,
                    const float* bias, int M, int N, int K, int HH, int batch,
                    float alpha, int mode)   // 0=plain 1=relu 2=nt 3=causal
    {
        dim3 g(N / GBN, (M + GBM - 1) / GBM, batch), blk(256);
        if (mode == 2)
            mfma_gemm_kernel<0, 1, 0><<<g, blk, 0, stream>>>(A, lda, sAn, sAh, B, ldb, sBn, sBh,
                                                             C, Cb, ldc, sCn, sCh, bias, M, N, K, HH, alpha);
        else if (mode == 1)
            mfma_gemm_kernel<1, 0, 0><<<g, blk, 0, stream>>>(A, lda, sAn, sAh, B, ldb, sBn, sBh,
                                                             C, Cb, ldc, sCn, sCh, bias, M, N, K, HH, alpha);
        else if (mode == 3)
            mfma_gemm_kernel<0, 0, 1><<<g, blk, 0, stream>>>(A, lda, sAn, sAh, B, ldb, sBn, sBh,
                                                             C, Cb, ldc, sCn, sCh, bias, M, N, K, HH, alpha);
        else
            mfma_gemm_kernel<0, 0, 0><<<g, blk, 0, stream>>>(A, lda, sAn, sAh, B, ldb, sBn, sBh,
                                                             C, Cb, ldc, sCn, sCh, bias, M, N, K, HH, alpha);
    };
    auto transposeF = [&](const float* src, int lds_, long ssn, long ssh,
                          u16* dst, int ldd, long dsn, long dsh,
                          int K, int N, int batch, int HH)
    {
        dim3 g(N / 32, K / 32, batch), blk(256);
        transpose_cvt_kernel<float><<<g, blk, 0, stream>>>(src, lds_, ssn, ssh, dst, ldd, dsn, dsh, HH);
    };
    auto transposeB = [&](const u16* src, int lds_, long ssn, long ssh,
                          u16* dst, int ldd, long dsn, long dsh,
                          int K, int N, int batch, int HH)
    {
        dim3 g(N / 32, K / 32, batch), blk(256);
        transpose_cvt_kernel<u16><<<g, blk, 0, stream>>>(src, lds_, ssn, ssh, dst, ldd, dsn, dsh, HH);
    };

    // ---- weight conversion (per call; deterministic) ----
    cvt_kernel<<<(NBATCH * DFEAT + 255) / 256, 256, 0, stream>>>(features, featb, NBATCH * DFEAT);
    concat_bias_kernel<<<(NLAY * QKVW + 255) / 256, 256, 0, stream>>>(sa_bq, sa_bk, sa_bv, qkv_bias);
    transposeF(vis_w, WDIM, 0, 0, vis_wT, DFEAT, 0, 0, DFEAT, WDIM, 1, 1);
    transposeF(sa_wq, WDIM, (long)WDIM * WDIM, 0, qkvT,                WDIM, (long)QKVW * WDIM, 0, WDIM, WDIM, NLAY, 1);
    transposeF(sa_wk, WDIM, (long)WDIM * WDIM, 0, qkvT + (long)WDIM * WDIM,     WDIM, (long)QKVW * WDIM, 0, WDIM, WDIM, NLAY, 1);
    transposeF(sa_wv, WDIM, (long)WDIM * WDIM, 0, qkvT + (long)2 * WDIM * WDIM, WDIM, (long)QKVW * WDIM, 0, WDIM, WDIM, NLAY, 1);
    transposeF(sa_wo, WDIM, (long)WDIM * WDIM, 0, sa_woT, WDIM, (long)WDIM * WDIM, 0, WDIM, WDIM, NLAY, 1);
    transposeF(ca_wv, WDIM, (long)WDIM * WDIM, 0, ca_wvT, WDIM, (long)WDIM * WDIM, 0, WDIM, WDIM, NLAY, 1);
    transposeF(ca_wo, WDIM, (long)WDIM * WDIM, 0, ca_woT, WDIM, (long)WDIM * WDIM, 0, WDIM, WDIM, NLAY, 1);
    transposeF(ff1_w, FFDIM, (long)WDIM * FFDIM, 0, ff1T, WDIM, (long)FFDIM * WDIM, 0, WDIM, FFDIM, NLAY, 1);
    transposeF(ff2_w, WDIM, (long)FFDIM * WDIM, 0, ff2T, FFDIM, (long)WDIM * FFDIM, 0, FFDIM, WDIM, NLAY, 1);
    transposeF(out_w, VOCAB, 0, 0, out_wT, WDIM, 0, 0, WDIM, VOCAB, 1, 1);

    // memory = features @ vis_w + vis_b   (8 x 512), keep f32 + bf16
    gemm(featb, DFEAT, 0, 0, vis_wT, DFEAT, 0, 0, memb, membf, WDIM, 0, 0,
         vis_b, NBATCH, WDIM, DFEAT, 1, 1, 1.f, 0);
    // x = emb[captions] + pe
    embed_kernel<<<NT, 128, 0, stream>>>(captions, emb, pe, x, xb);

    const float iscale = 1.f / sqrtf((float)DHEAD);
    const long TQ = (long)TLEN * QKVW;
    const long TW = (long)TLEN * WDIM;
    const long TT = (long)TLEN * TLEN;
    for (int l = 0; l < NLAY; l++) {
        long wo  = (long)l * WDIM * WDIM;
        long bo_ = (long)l * WDIM;
        // ---- self-attention: fused QKV projection (N=1536) ----
        gemm(xb, WDIM, 0, 0, qkvT + (long)l * QKVW * WDIM, WDIM, 0, 0,
             nullptr, qkvb, QKVW, 0, 0, qkv_bias + (long)l * QKVW,
             NT, QKVW, WDIM, 1, 1, 1.f, 0);
        // V^T per (n,h): qkvb[n*T+t][1024 + h*128 + d] -> vtb [n][h][d][t]
        transposeB(qkvb + 2 * WDIM, QKVW, TQ, DHEAD,
                   vtb, TLEN, (long)NHEADS * DHEAD * TLEN, (long)DHEAD * TLEN,
                   TLEN, DHEAD, NBATCH * NHEADS, NHEADS);
        // scores = (Q_h @ K_h^T) * iscale  (causal: skip fully-masked tiles)
        gemm(qkvb, QKVW, TQ, DHEAD, qkvb + WDIM, QKVW, TQ, DHEAD,
             scores, nullptr, TLEN, (long)NHEADS * TT, TT,
             nullptr, TLEN, TLEN, DHEAD, NHEADS, NBATCH * NHEADS, iscale, 3);
        softmax_causal_kernel<<<NBATCH * NHEADS * TLEN, 256, 0, stream>>>(scores, pb);
        // y = P @ V_h  (B = V^T tile, (N=d, K=t))
        gemm(pb, TLEN, (long)NHEADS * TT, TT,
             vtb, TLEN, (long)NHEADS * DHEAD * TLEN, (long)DHEAD * TLEN,
             nullptr, yb, WDIM, TW, DHEAD,
             nullptr, TLEN, DHEAD, TLEN, NHEADS, NBATCH * NHEADS, 1.f, 0);
        // t2 = y @ wo + bo
        gemm(yb, WDIM, 0, 0, sa_woT + wo, WDIM, 0, 0, t2, nullptr, WDIM, 0, 0,
             sa_bo + bo_, NT, WDIM, WDIM, 1, 1, 1.f, 0);
        add_ln_kernel<<<NT, 256, 0, stream>>>(x, xb, t2, 1, ln1_w + bo_, ln1_b + bo_);
        // ---- cross-attention (collapsed: softmax over len-1 == 1) ----
        gemm(membf, WDIM, 0, 0, ca_wvT + wo, WDIM, 0, 0, nullptr, cvb, WDIM, 0, 0,
             ca_bv + bo_, NBATCH, WDIM, WDIM, 1, 1, 1.f, 0);
        gemm(cvb, WDIM, 0, 0, ca_woT + wo, WDIM, 0, 0, cav, nullptr, WDIM, 0, 0,
             ca_bo + bo_, NBATCH, WDIM, WDIM, 1, 1, 1.f, 0);
        add_ln_kernel<<<NT, 256, 0, stream>>>(x, xb, cav, TLEN, ln2_w + bo_, ln2_b + bo_);
        // ---- FFN ----
        gemm(xb, WDIM, 0, 0, ff1T + (long)l * FFDIM * WDIM, WDIM, 0, 0,
             nullptr, hb, FFDIM, 0, 0, ff1_b + (long)l * FFDIM,
             NT, FFDIM, WDIM, 1, 1, 1.f, 1);
        gemm(hb, FFDIM, 0, 0, ff2T + (long)l * WDIM * FFDIM, FFDIM, 0, 0,
             t2, nullptr, WDIM, 0, 0, ff2_b + bo_, NT, WDIM, FFDIM, 1, 1, 1.f, 0);
        add_ln_kernel<<<NT, 256, 0, stream>>>(x, xb, t2, 1, ln3_w + bo_, ln3_b + bo_);
    }
    // out = x @ out_w + out_b   (4096 x 32000) — coalesced non-temporal f32 stores
    gemm(xb, WDIM, 0, 0, out_wT, WDIM, 0, 0, (float*)d_out, nullptr, VOCAB, 0, 0,
         out_b, NT, VOCAB, WDIM, 1, 1, 1.f, 2);
}

// Round 7
// 771.952 us; speedup vs baseline: 5.1780x; 1.0666x over previous
//
#include <hip/hip_runtime.h>
#include <math.h>

#define WDIM   512
#define TLEN   512
#define NBATCH 8
#define NHEADS 4
#define DHEAD  128
#define VOCAB  32000
#define NLAY   2
#define FFDIM  2048
#define DFEAT  1024
#define NT     (NBATCH * TLEN)   // 4096 rows
#define QKVW   (3 * WDIM)        // 1536

typedef unsigned short u16;
typedef __attribute__((ext_vector_type(8))) short bf16x8;
typedef __attribute__((ext_vector_type(4))) float f32x4;

__device__ inline u16 f2bf(float f) {
    union { float f; unsigned u; } v; v.f = f;
    unsigned r = v.u + 0x7fffu + ((v.u >> 16) & 1u);
    return (u16)(r >> 16);
}
__device__ inline u16 to_bf(float f) { return f2bf(f); }
__device__ inline u16 to_bf(u16 v)  { return v; }

// ---------------- f32 -> bf16 flat convert ----------------
__global__ __launch_bounds__(256)
void cvt_kernel(const float* __restrict__ s, u16* __restrict__ d, int n)
{
    int i = blockIdx.x * 256 + threadIdx.x;
    if (i < n) d[i] = f2bf(s[i]);
}

// ---------------- concat per-layer QKV bias: [bq;bk;bv] -> (NLAY,1536) ----------------
__global__ __launch_bounds__(256)
void concat_bias_kernel(const float* __restrict__ bq, const float* __restrict__ bk,
                        const float* __restrict__ bv, float* __restrict__ dst)
{
    int i = blockIdx.x * 256 + threadIdx.x;
    if (i >= NLAY * QKVW) return;
    int l = i / QKVW, j = i - l * QKVW;
    float v = (j < WDIM) ? bq[l * WDIM + j]
            : (j < 2 * WDIM) ? bk[l * WDIM + j - WDIM]
            : bv[l * WDIM + j - 2 * WDIM];
    dst[i] = v;
}

// ---------------- tiled transpose + convert: src (K,N) -> dst (N,K) bf16 ----------------
template<typename T>
__global__ __launch_bounds__(256)
void transpose_cvt_kernel(const T* __restrict__ src, int lds_, long ssn, long ssh,
                          u16* __restrict__ dst, int ldd, long dsn, long dsh,
                          int HH)
{
    int z = blockIdx.z;
    int zn = z / HH, zh = z - zn * HH;
    src += (long)zn * ssn + (long)zh * ssh;
    dst += (long)zn * dsn + (long)zh * dsh;
    __shared__ T tile[32][33];
    int n0 = blockIdx.x * 32, k0 = blockIdx.y * 32;
    int tx = threadIdx.x & 31, ty = threadIdx.x >> 5;  // 32 x 8
    #pragma unroll
    for (int i = 0; i < 32; i += 8)
        tile[ty + i][tx] = src[(long)(k0 + ty + i) * lds_ + n0 + tx];
    __syncthreads();
    #pragma unroll
    for (int i = 0; i < 32; i += 8)
        dst[(long)(n0 + ty + i) * ldd + k0 + tx] = to_bf(tile[tx][ty + i]);
}

// ---------------- embed + positional encoding ----------------
__global__ __launch_bounds__(128)
void embed_kernel(const int* __restrict__ captions, const float* __restrict__ emb,
                  const float* __restrict__ pe, float* __restrict__ x, u16* __restrict__ xb)
{
    int r = blockIdx.x;            // 0..NT-1
    int t = r % TLEN;
    int cap = captions[r];
    const float4* e4 = (const float4*)(emb + (long)cap * WDIM);
    const float4* p4 = (const float4*)(pe + (long)t * WDIM);
    float4 a = e4[threadIdx.x], b = p4[threadIdx.x];
    float4 o = make_float4(a.x + b.x, a.y + b.y, a.z + b.z, a.w + b.w);
    ((float4*)(x + (long)r * WDIM))[threadIdx.x] = o;
    ushort4 ob = make_ushort4(f2bf(o.x), f2bf(o.y), f2bf(o.z), f2bf(o.w));
    ((ushort4*)(xb + (long)r * WDIM))[threadIdx.x] = ob;
}

// ---------------- bf16 MFMA GEMM: 2-phase double-buffered pipeline (T3-min) ----------
// C[z] = act(alpha * A[z] @ B[z]^T + bias); A (M,K) bf16 row-major,
// B stored TRANSPOSED (N,K) bf16 row-major. C f32 and/or Cb bf16 outputs.
// Pipeline: STAGE(buf^1, ks+1) issued BEFORE ds_read+MFMA of buf[ks]; one
// vmcnt(0)+barrier per K-step (the __syncthreads) -> load latency hides
// under the MFMA phase instead of being drained immediately.
// NTST: non-temporal LDS-staged coalesced f32x4 C stores.
// CAUSAL: skip tiles fully above the diagonal.
#define GBM 128
#define GBN 128
#define GBK 32

template<int RELU, int NTST, int CAUSAL>
__global__ __launch_bounds__(256)
void mfma_gemm_kernel(const u16* __restrict__ A, int lda, long sAn, long sAh,
                      const u16* __restrict__ B, int ldb, long sBn, long sBh,
                      float* __restrict__ C, u16* __restrict__ Cb, int ldc, long sCn, long sCh,
                      const float* __restrict__ bias,
                      int M, int N, int K, int HH, float alpha)
{
    int z = blockIdx.z;
    int zn = z / HH, zh = z - zn * HH;
    A += (long)zn * sAn + (long)zh * sAh;
    B += (long)zn * sBn + (long)zh * sBh;
    long coff = (long)zn * sCn + (long)zh * sCh;

    // XCD-chunked bijective swizzle (m204)
    int nwg  = gridDim.x * gridDim.y;
    int orig = blockIdx.y * gridDim.x + blockIdx.x;
    int q = nwg >> 3, r = nwg & 7, xcd = orig & 7, rest = orig >> 3;
    int nw = (xcd < r ? xcd * (q + 1) : r * (q + 1) + (xcd - r) * q) + rest;
    int bx = nw / gridDim.y, by = nw - bx * gridDim.y;
    int bm = by * GBM, bn = bx * GBN;

    if (CAUSAL && bn >= bm + GBM) return;   // fully-masked tile

    __shared__ u16 As[2][GBM * GBK];   // [buf][row*GBK + k], k contiguous
    __shared__ u16 Bs[2][GBN * GBK];

    int tid = threadIdx.x;
    int w = tid >> 6, lane = tid & 63;
    int wr = w >> 1, wc = w & 1;         // 2x2 wave grid, 64x64 per wave
    int lrow = lane & 15, kgrp = lane >> 4;

    // per-thread staging coords (chunk c -> row c/4, k-offset (c%4)*8)
    int c0row = tid >> 2, c0ko = (tid & 3) << 3;
    long ldsOff = (size_t)(w * 64) * 8;

    auto STAGE = [&](int buf, int ks) {
        int k0 = ks * GBK;
        #pragma unroll
        for (int i = 0; i < 2; i++) {
            int row = c0row + i * 64;
            int gr = bm + row; if (gr >= M) gr = M - 1;   // clamp (ragged M=8)
            const u16* srcA = A + (long)gr * lda + k0 + c0ko;
            u16* dstA = &As[buf][ldsOff + (size_t)i * 256 * 8];
            __builtin_amdgcn_global_load_lds((const __attribute__((address_space(1))) void*)srcA,
                                             (__attribute__((address_space(3))) void*)dstA, 16, 0, 0);
            const u16* srcB = B + (long)(bn + row) * ldb + k0 + c0ko;
            u16* dstB = &Bs[buf][ldsOff + (size_t)i * 256 * 8];
            __builtin_amdgcn_global_load_lds((const __attribute__((address_space(1))) void*)srcB,
                                             (__attribute__((address_space(3))) void*)dstB, 16, 0, 0);
        }
    };

    f32x4 acc[4][4] = {};
    int nsteps = K / GBK;

    STAGE(0, 0);
    __syncthreads();

    for (int ks = 0; ks < nsteps; ks++) {
        int cur = ks & 1;
        if (ks + 1 < nsteps) STAGE(cur ^ 1, ks + 1);   // issue next-tile loads FIRST
        bf16x8 av[4], bv[4];
        #pragma unroll
        for (int m = 0; m < 4; m++)
            av[m] = *(const bf16x8*)&As[cur][(wr * 64 + m * 16 + lrow) * GBK + kgrp * 8];
        #pragma unroll
        for (int n = 0; n < 4; n++)
            bv[n] = *(const bf16x8*)&Bs[cur][(wc * 64 + n * 16 + lrow) * GBK + kgrp * 8];
        #pragma unroll
        for (int m = 0; m < 4; m++)
            #pragma unroll
            for (int n = 0; n < 4; n++)
                acc[m][n] = __builtin_amdgcn_mfma_f32_16x16x32_bf16(av[m], bv[n], acc[m][n], 0, 0, 0);
        __syncthreads();   // vmcnt(0)+lgkmcnt(0)+barrier: next buf ready, prev reads done
    }

    // C/D layout: col = lane&15, row = (lane>>4)*4 + reg   [m89/m91 verified]
    if (NTST) {
        // LDS-staged coalesced NT epilogue: 4 passes of 32 rows x 128 cols f32.
        float* ls = (float*)&As[0][0];     // 32*128 f32 = 16 KB (As region)
        C += coff;
        #pragma unroll
        for (int pass = 0; pass < 4; pass++) {
            if (wr == (pass >> 1)) {
                #pragma unroll
                for (int m2 = 0; m2 < 2; m2++) {
                    int m = (pass & 1) * 2 + m2;
                    #pragma unroll
                    for (int n = 0; n < 4; n++) {
                        int gc = wc * 64 + n * 16 + lrow;
                        float bvv = bias ? bias[bn + gc] : 0.f;
                        #pragma unroll
                        for (int r2 = 0; r2 < 4; r2++) {
                            float v2 = acc[m][n][r2] * alpha + bvv;
                            if (RELU) v2 = fmaxf(v2, 0.f);
                            ls[(m2 * 16 + kgrp * 4 + r2) * 128 + gc] = v2;
                        }
                    }
                }
            }
            __syncthreads();
            #pragma unroll
            for (int i = 0; i < 4; i++) {
                int j = tid + i * 256;            // 0..1023 f32x4
                int row = j >> 5, cg = j & 31;
                int gr = bm + pass * 32 + row;
                if (gr < M) {
                    f32x4 v4 = *(const f32x4*)&ls[row * 128 + cg * 4];
                    __builtin_nontemporal_store(v4, (f32x4*)&C[(long)gr * ldc + bn + cg * 4]);
                }
            }
            __syncthreads();
        }
        return;
    }

    if (C)  C  += coff;
    if (Cb) Cb += coff;
    #pragma unroll
    for (int m = 0; m < 4; m++) {
        int rb = bm + wr * 64 + m * 16 + kgrp * 4;
        #pragma unroll
        for (int n = 0; n < 4; n++) {
            int gc = bn + wc * 64 + n * 16 + lrow;
            float bvv = bias ? bias[gc] : 0.f;
            #pragma unroll
            for (int r2 = 0; r2 < 4; r2++) {
                int gr = rb + r2;
                if (gr < M) {
                    float v2 = acc[m][n][r2] * alpha + bvv;
                    if (RELU) v2 = fmaxf(v2, 0.f);
                    if (C)  C[(long)gr * ldc + gc]  = v2;
                    if (Cb) Cb[(long)gr * ldc + gc] = f2bf(v2);
                }
            }
        }
    }
}

// ---------------- causal softmax: f32 scores -> bf16 P ----------------
__global__ __launch_bounds__(256)
void softmax_causal_kernel(const float* __restrict__ scores, u16* __restrict__ pb)
{
    long row = blockIdx.x;                 // n*H*T + h*T + s
    int s = (int)(row % TLEN);
    const float* p = scores + row * TLEN;
    u16* o = pb + row * TLEN;
    int tid = threadIdx.x;
    float v0 = p[tid], v1 = p[tid + 256];
    bool m0 = (tid <= s), m1 = (tid + 256 <= s);
    __shared__ float red[256];
    float mx = fmaxf(m0 ? v0 : -INFINITY, m1 ? v1 : -INFINITY);
    red[tid] = mx; __syncthreads();
    for (int off = 128; off > 0; off >>= 1) {
        if (tid < off) red[tid] = fmaxf(red[tid], red[tid + off]);
        __syncthreads();
    }
    mx = red[0]; __syncthreads();
    float e0 = m0 ? expf(v0 - mx) : 0.f;
    float e1 = m1 ? expf(v1 - mx) : 0.f;
    red[tid] = e0 + e1; __syncthreads();
    for (int off = 128; off > 0; off >>= 1) {
        if (tid < off) red[tid] += red[tid + off];
        __syncthreads();
    }
    float inv = 1.f / red[0];
    o[tid]       = f2bf(e0 * inv);
    o[tid + 256] = f2bf(e1 * inv);
}

// ---------------- x = LayerNorm(x + t2); writes f32 x and bf16 xb ----------------
__global__ __launch_bounds__(256)
void add_ln_kernel(float* __restrict__ x, u16* __restrict__ xb,
                   const float* __restrict__ t2, long t2div,
                   const float* __restrict__ w, const float* __restrict__ b)
{
    long r = blockIdx.x;
    float* xr = x + r * WDIM;
    u16* xbr = xb + r * WDIM;
    const float* tr = t2 + (r / t2div) * WDIM;
    int tid = threadIdx.x;
    float v0 = xr[tid] + tr[tid];
    float v1 = xr[tid + 256] + tr[tid + 256];
    __shared__ float red[256];
    red[tid] = v0 + v1; __syncthreads();
    for (int off = 128; off > 0; off >>= 1) {
        if (tid < off) red[tid] += red[tid + off];
        __syncthreads();
    }
    float mean = red[0] * (1.f / WDIM); __syncthreads();
    float d0 = v0 - mean, d1 = v1 - mean;
    red[tid] = d0 * d0 + d1 * d1; __syncthreads();
    for (int off = 128; off > 0; off >>= 1) {
        if (tid < off) red[tid] += red[tid + off];
        __syncthreads();
    }
    float rstd = 1.f / sqrtf(red[0] * (1.f / WDIM) + 1e-5f);
    float o0 = d0 * rstd * w[tid] + b[tid];
    float o1 = d1 * rstd * w[tid + 256] + b[tid + 256];
    xr[tid] = o0;        xr[tid + 256] = o1;
    xbr[tid] = f2bf(o0); xbr[tid + 256] = f2bf(o1);
}

extern "C" void kernel_launch(void* const* d_in, const int* in_sizes, int n_in,
                              void* d_out, int out_size, void* d_ws, size_t ws_size,
                              hipStream_t stream)
{
    const float* features = (const float*)d_in[0];
    const int*   captions = (const int*)  d_in[1];
    const float* emb      = (const float*)d_in[2];
    const float* pe       = (const float*)d_in[3];
    const float* vis_w    = (const float*)d_in[4];
    const float* vis_b    = (const float*)d_in[5];
    const float* sa_wq    = (const float*)d_in[6];
    const float* sa_bq    = (const float*)d_in[7];
    const float* sa_wk    = (const float*)d_in[8];
    const float* sa_bk    = (const float*)d_in[9];
    const float* sa_wv    = (const float*)d_in[10];
    const float* sa_bv    = (const float*)d_in[11];
    const float* sa_wo    = (const float*)d_in[12];
    const float* sa_bo    = (const float*)d_in[13];
    // ca_wq/bq/wk/bk (14..17) unused: len-1 memory => softmax == 1 identically
    const float* ca_wv    = (const float*)d_in[18];
    const float* ca_bv    = (const float*)d_in[19];
    const float* ca_wo    = (const float*)d_in[20];
    const float* ca_bo    = (const float*)d_in[21];
    const float* ff1_w    = (const float*)d_in[22];
    const float* ff1_b    = (const float*)d_in[23];
    const float* ff2_w    = (const float*)d_in[24];
    const float* ff2_b    = (const float*)d_in[25];
    const float* ln1_w    = (const float*)d_in[26];
    const float* ln1_b    = (const float*)d_in[27];
    const float* ln2_w    = (const float*)d_in[28];
    const float* ln2_b    = (const float*)d_in[29];
    const float* ln3_w    = (const float*)d_in[30];
    const float* ln3_b    = (const float*)d_in[31];
    const float* out_w    = (const float*)d_in[32];
    const float* out_b    = (const float*)d_in[33];

    // ---- workspace carve ----
    char* p = (char*)d_ws;
    auto alloc = [&](size_t bytes) { char* r = p; p += (bytes + 255) & ~(size_t)255; return r; };
    float* x    = (float*)alloc((size_t)NT * WDIM * 4);
    float* t2   = (float*)alloc((size_t)NT * WDIM * 4);
    float* memb = (float*)alloc((size_t)NBATCH * WDIM * 4);
    float* cav  = (float*)alloc((size_t)NBATCH * WDIM * 4);
    // union region: scores f32 (SA phase) | yb bf16 (PV->Oproj) | hb bf16 (FFN)
    char*  reg1 = alloc((size_t)NBATCH * NHEADS * TLEN * TLEN * 4);
    float* scores = (float*)reg1;
    u16*   yb     = (u16*)reg1;
    u16*   hb     = (u16*)reg1;
    u16* xb    = (u16*)alloc((size_t)NT * WDIM * 2);
    u16* qkvb  = (u16*)alloc((size_t)NT * QKVW * 2);
    u16* vtb   = (u16*)alloc((size_t)NT * WDIM * 2);
    u16* pb    = (u16*)alloc((size_t)NBATCH * NHEADS * TLEN * TLEN * 2);
    u16* featb = (u16*)alloc((size_t)NBATCH * DFEAT * 2);
    u16* membf = (u16*)alloc((size_t)NBATCH * WDIM * 2);
    u16* cvb   = (u16*)alloc((size_t)NBATCH * WDIM * 2);
    float* qkv_bias = (float*)alloc((size_t)NLAY * QKVW * 4);
    u16* vis_wT = (u16*)alloc((size_t)WDIM * DFEAT * 2);
    u16* qkvT   = (u16*)alloc((size_t)NLAY * QKVW * WDIM * 2);
    u16* sa_woT = (u16*)alloc((size_t)NLAY * WDIM * WDIM * 2);
    u16* ca_wvT = (u16*)alloc((size_t)NLAY * WDIM * WDIM * 2);
    u16* ca_woT = (u16*)alloc((size_t)NLAY * WDIM * WDIM * 2);
    u16* ff1T   = (u16*)alloc((size_t)NLAY * WDIM * FFDIM * 2);
    u16* ff2T   = (u16*)alloc((size_t)NLAY * FFDIM * WDIM * 2);
    u16* out_wT = (u16*)alloc((size_t)WDIM * VOCAB * 2);

    auto gemm = [&](const u16* A, int lda, long sAn, long sAh,
                    const u16* B, int ldb, long sBn, long sBh,
                    float* C, u16* Cb, int ldc, long sCn, long sCh,
                    const float* bias, int M, int N, int K, int HH, int batch,
                    float alpha, int mode)   // 0=plain 1=relu 2=nt 3=causal
    {
        dim3 g(N / GBN, (M + GBM - 1) / GBM, batch), blk(256);
        if (mode == 2)
            mfma_gemm_kernel<0, 1, 0><<<g, blk, 0, stream>>>(A, lda, sAn, sAh, B, ldb, sBn, sBh,
                                                             C, Cb, ldc, sCn, sCh, bias, M, N, K, HH, alpha);
        else if (mode == 1)
            mfma_gemm_kernel<1, 0, 0><<<g, blk, 0, stream>>>(A, lda, sAn, sAh, B, ldb, sBn, sBh,
                                                             C, Cb, ldc, sCn, sCh, bias, M, N, K, HH, alpha);
        else if (mode == 3)
            mfma_gemm_kernel<0, 0, 1><<<g, blk, 0, stream>>>(A, lda, sAn, sAh, B, ldb, sBn, sBh,
                                                             C, Cb, ldc, sCn, sCh, bias, M, N, K, HH, alpha);
        else
            mfma_gemm_kernel<0, 0, 0><<<g, blk, 0, stream>>>(A, lda, sAn, sAh, B, ldb, sBn, sBh,
                                                             C, Cb, ldc, sCn, sCh, bias, M, N, K, HH, alpha);
    };
    auto transposeF = [&](const float* src, int lds_, long ssn, long ssh,
                          u16* dst, int ldd, long dsn, long dsh,
                          int K, int N, int batch, int HH)
    {
        dim3 g(N / 32, K / 32, batch), blk(256);
        transpose_cvt_kernel<float><<<g, blk, 0, stream>>>(src, lds_, ssn, ssh, dst, ldd, dsn, dsh, HH);
    };
    auto transposeB = [&](const u16* src, int lds_, long ssn, long ssh,
                          u16* dst, int ldd, long dsn, long dsh,
                          int K, int N, int batch, int HH)
    {
        dim3 g(N / 32, K / 32, batch), blk(256);
        transpose_cvt_kernel<u16><<<g, blk, 0, stream>>>(src, lds_, ssn, ssh, dst, ldd, dsn, dsh, HH);
    };

    // ---- weight conversion (per call; deterministic) ----
    cvt_kernel<<<(NBATCH * DFEAT + 255) / 256, 256, 0, stream>>>(features, featb, NBATCH * DFEAT);
    concat_bias_kernel<<<(NLAY * QKVW + 255) / 256, 256, 0, stream>>>(sa_bq, sa_bk, sa_bv, qkv_bias);
    transposeF(vis_w, WDIM, 0, 0, vis_wT, DFEAT, 0, 0, DFEAT, WDIM, 1, 1);
    transposeF(sa_wq, WDIM, (long)WDIM * WDIM, 0, qkvT,                WDIM, (long)QKVW * WDIM, 0, WDIM, WDIM, NLAY, 1);
    transposeF(sa_wk, WDIM, (long)WDIM * WDIM, 0, qkvT + (long)WDIM * WDIM,     WDIM, (long)QKVW * WDIM, 0, WDIM, WDIM, NLAY, 1);
    transposeF(sa_wv, WDIM, (long)WDIM * WDIM, 0, qkvT + (long)2 * WDIM * WDIM, WDIM, (long)QKVW * WDIM, 0, WDIM, WDIM, NLAY, 1);
    transposeF(sa_wo, WDIM, (long)WDIM * WDIM, 0, sa_woT, WDIM, (long)WDIM * WDIM, 0, WDIM, WDIM, NLAY, 1);
    transposeF(ca_wv, WDIM, (long)WDIM * WDIM, 0, ca_wvT, WDIM, (long)WDIM * WDIM, 0, WDIM, WDIM, NLAY, 1);
    transposeF(ca_wo, WDIM, (long)WDIM * WDIM, 0, ca_woT, WDIM, (long)WDIM * WDIM, 0, WDIM, WDIM, NLAY, 1);
    transposeF(ff1_w, FFDIM, (long)WDIM * FFDIM, 0, ff1T, WDIM, (long)FFDIM * WDIM, 0, WDIM, FFDIM, NLAY, 1);
    transposeF(ff2_w, WDIM, (long)FFDIM * WDIM, 0, ff2T, FFDIM, (long)WDIM * FFDIM, 0, FFDIM, WDIM, NLAY, 1);
    transposeF(out_w, VOCAB, 0, 0, out_wT, WDIM, 0, 0, WDIM, VOCAB, 1, 1);

    // memory = features @ vis_w + vis_b   (8 x 512), keep f32 + bf16
    gemm(featb, DFEAT, 0, 0, vis_wT, DFEAT, 0, 0, memb, membf, WDIM, 0, 0,
         vis_b, NBATCH, WDIM, DFEAT, 1, 1, 1.f, 0);
    // x = emb[captions] + pe
    embed_kernel<<<NT, 128, 0, stream>>>(captions, emb, pe, x, xb);

    const float iscale = 1.f / sqrtf((float)DHEAD);
    const long TQ = (long)TLEN * QKVW;
    const long TW = (long)TLEN * WDIM;
    const long TT = (long)TLEN * TLEN;
    for (int l = 0; l < NLAY; l++) {
        long wo  = (long)l * WDIM * WDIM;
        long bo_ = (long)l * WDIM;
        // ---- self-attention: fused QKV projection (N=1536) ----
        gemm(xb, WDIM, 0, 0, qkvT + (long)l * QKVW * WDIM, WDIM, 0, 0,
             nullptr, qkvb, QKVW, 0, 0, qkv_bias + (long)l * QKVW,
             NT, QKVW, WDIM, 1, 1, 1.f, 0);
        // V^T per (n,h): qkvb[n*T+t][1024 + h*128 + d] -> vtb [n][h][d][t]
        transposeB(qkvb + 2 * WDIM, QKVW, TQ, DHEAD,
                   vtb, TLEN, (long)NHEADS * DHEAD * TLEN, (long)DHEAD * TLEN,
                   TLEN, DHEAD, NBATCH * NHEADS, NHEADS);
        // scores = (Q_h @ K_h^T) * iscale  (causal: skip fully-masked tiles)
        gemm(qkvb, QKVW, TQ, DHEAD, qkvb + WDIM, QKVW, TQ, DHEAD,
             scores, nullptr, TLEN, (long)NHEADS * TT, TT,
             nullptr, TLEN, TLEN, DHEAD, NHEADS, NBATCH * NHEADS, iscale, 3);
        softmax_causal_kernel<<<NBATCH * NHEADS * TLEN, 256, 0, stream>>>(scores, pb);
        // y = P @ V_h  (B = V^T tile, (N=d, K=t))
        gemm(pb, TLEN, (long)NHEADS * TT, TT,
             vtb, TLEN, (long)NHEADS * DHEAD * TLEN, (long)DHEAD * TLEN,
             nullptr, yb, WDIM, TW, DHEAD,
             nullptr, TLEN, DHEAD, TLEN, NHEADS, NBATCH * NHEADS, 1.f, 0);
        // t2 = y @ wo + bo
        gemm(yb, WDIM, 0, 0, sa_woT + wo, WDIM, 0, 0, t2, nullptr, WDIM, 0, 0,
             sa_bo + bo_, NT, WDIM, WDIM, 1, 1, 1.f, 0);
        add_ln_kernel<<<NT, 256, 0, stream>>>(x, xb, t2, 1, ln1_w + bo_, ln1_b + bo_);
        // ---- cross-attention (collapsed: softmax over len-1 == 1) ----
        gemm(membf, WDIM, 0, 0, ca_wvT + wo, WDIM, 0, 0, nullptr, cvb, WDIM, 0, 0,
             ca_bv + bo_, NBATCH, WDIM, WDIM, 1, 1, 1.f, 0);
        gemm(cvb, WDIM, 0, 0, ca_woT + wo, WDIM, 0, 0, cav, nullptr, WDIM, 0, 0,
             ca_bo + bo_, NBATCH, WDIM, WDIM, 1, 1, 1.f, 0);
        add_ln_kernel<<<NT, 256, 0, stream>>>(x, xb, cav, TLEN, ln2_w + bo_, ln2_b + bo_);
        // ---- FFN ----
        gemm(xb, WDIM, 0, 0, ff1T + (long)l * FFDIM * WDIM, WDIM, 0, 0,
             nullptr, hb, FFDIM, 0, 0, ff1_b + (long)l * FFDIM,
             NT, FFDIM, WDIM, 1, 1, 1.f, 1);
        gemm(hb, FFDIM, 0, 0, ff2T + (long)l * WDIM * FFDIM, FFDIM, 0, 0,
             t2, nullptr, WDIM, 0, 0, ff2_b + bo_, NT, WDIM, FFDIM, 1, 1, 1.f, 0);
        add_ln_kernel<<<NT, 256, 0, stream>>>(x, xb, t2, 1, ln3_w + bo_, ln3_b + bo_);
    }
    // out = x @ out_w + out_b   (4096 x 32000) — coalesced non-temporal f32 stores
    gemm(xb, WDIM, 0, 0, out_wT, WDIM, 0, 0, (float*)d_out, nullptr, VOCAB, 0, 0,
         out_b, NT, VOCAB, WDIM, 1, 1, 1.f, 2);
}

// Round 8
// 730.526 us; speedup vs baseline: 5.4717x; 1.0567x over previous
//
#include <hip/hip_runtime.h>
#include <math.h>

#define WDIM   512
#define TLEN   512
#define NBATCH 8
#define NHEADS 4
#define DHEAD  128
#define VOCAB  32000
#define NLAY   2
#define FFDIM  2048
#define DFEAT  1024
#define NT     (NBATCH * TLEN)   // 4096 rows
#define QKVW   (3 * WDIM)        // 1536

typedef unsigned short u16;
typedef __attribute__((ext_vector_type(8))) short bf16x8;
typedef __attribute__((ext_vector_type(4))) float f32x4;

__device__ inline u16 f2bf(float f) {
    union { float f; unsigned u; } v; v.f = f;
    unsigned r = v.u + 0x7fffu + ((v.u >> 16) & 1u);
    return (u16)(r >> 16);
}
__device__ inline u16 to_bf(float f) { return f2bf(f); }
__device__ inline u16 to_bf(u16 v)  { return v; }

// ---------------- f32 -> bf16 flat convert ----------------
__global__ __launch_bounds__(256)
void cvt_kernel(const float* __restrict__ s, u16* __restrict__ d, int n)
{
    int i = blockIdx.x * 256 + threadIdx.x;
    if (i < n) d[i] = f2bf(s[i]);
}

// ---------------- concat per-layer QKV bias: [bq;bk;bv] -> (NLAY,1536) ----------------
__global__ __launch_bounds__(256)
void concat_bias_kernel(const float* __restrict__ bq, const float* __restrict__ bk,
                        const float* __restrict__ bv, float* __restrict__ dst)
{
    int i = blockIdx.x * 256 + threadIdx.x;
    if (i >= NLAY * QKVW) return;
    int l = i / QKVW, j = i - l * QKVW;
    float v = (j < WDIM) ? bq[l * WDIM + j]
            : (j < 2 * WDIM) ? bk[l * WDIM + j - WDIM]
            : bv[l * WDIM + j - 2 * WDIM];
    dst[i] = v;
}

// ---------------- tiled transpose + convert: src (K,N) -> dst (N,K) bf16 ----------------
template<typename T>
__global__ __launch_bounds__(256)
void transpose_cvt_kernel(const T* __restrict__ src, int lds_, long ssn, long ssh,
                          u16* __restrict__ dst, int ldd, long dsn, long dsh,
                          int HH)
{
    int z = blockIdx.z;
    int zn = z / HH, zh = z - zn * HH;
    src += (long)zn * ssn + (long)zh * ssh;
    dst += (long)zn * dsn + (long)zh * dsh;
    __shared__ T tile[32][33];
    int n0 = blockIdx.x * 32, k0 = blockIdx.y * 32;
    int tx = threadIdx.x & 31, ty = threadIdx.x >> 5;  // 32 x 8
    #pragma unroll
    for (int i = 0; i < 32; i += 8)
        tile[ty + i][tx] = src[(long)(k0 + ty + i) * lds_ + n0 + tx];
    __syncthreads();
    #pragma unroll
    for (int i = 0; i < 32; i += 8)
        dst[(long)(n0 + ty + i) * ldd + k0 + tx] = to_bf(tile[tx][ty + i]);
}

// ---------------- embed + positional encoding ----------------
__global__ __launch_bounds__(128)
void embed_kernel(const int* __restrict__ captions, const float* __restrict__ emb,
                  const float* __restrict__ pe, float* __restrict__ x, u16* __restrict__ xb)
{
    int r = blockIdx.x;            // 0..NT-1
    int t = r % TLEN;
    int cap = captions[r];
    const float4* e4 = (const float4*)(emb + (long)cap * WDIM);
    const float4* p4 = (const float4*)(pe + (long)t * WDIM);
    float4 a = e4[threadIdx.x], b = p4[threadIdx.x];
    float4 o = make_float4(a.x + b.x, a.y + b.y, a.z + b.z, a.w + b.w);
    ((float4*)(x + (long)r * WDIM))[threadIdx.x] = o;
    ushort4 ob = make_ushort4(f2bf(o.x), f2bf(o.y), f2bf(o.z), f2bf(o.w));
    ((ushort4*)(xb + (long)r * WDIM))[threadIdx.x] = ob;
}

// ---------------- bf16 MFMA GEMM: dbuf + counted-vmcnt pipeline (T3+T4-lite) ------
// C[z] = act(alpha * A[z] @ B[z]^T + bias[zn]); A (M,K) bf16 row-major,
// B stored TRANSPOSED (N,K) bf16 row-major. C f32 and/or Cb bf16 outputs.
// Per K-step: STAGE(next) -> s_waitcnt vmcnt(4) (current buffer's 4 loads done,
// next's 4 STAY IN FLIGHT across the barrier) -> s_barrier -> ds_read+MFMA ->
// s_barrier. Never drains vmcnt to 0 mid-loop (T4).
// NTST: non-temporal LDS-staged coalesced f32x4 C stores.
// CAUSAL: skip tiles fully above the diagonal.
#define GBM 128
#define GBN 128
#define GBK 32

template<int RELU, int NTST, int CAUSAL>
__global__ __launch_bounds__(256)
void mfma_gemm_kernel(const u16* __restrict__ A, int lda, long sAn, long sAh,
                      const u16* __restrict__ B, int ldb, long sBn, long sBh,
                      float* __restrict__ C, u16* __restrict__ Cb, int ldc, long sCn, long sCh,
                      const float* __restrict__ bias, long sbias,
                      int M, int N, int K, int HH, float alpha)
{
    int z = blockIdx.z;
    int zn = z / HH, zh = z - zn * HH;
    A += (long)zn * sAn + (long)zh * sAh;
    B += (long)zn * sBn + (long)zh * sBh;
    long coff = (long)zn * sCn + (long)zh * sCh;
    if (bias) bias += (long)zn * sbias;

    // XCD-chunked bijective swizzle (m204)
    int nwg  = gridDim.x * gridDim.y;
    int orig = blockIdx.y * gridDim.x + blockIdx.x;
    int q = nwg >> 3, r = nwg & 7, xcd = orig & 7, rest = orig >> 3;
    int nw = (xcd < r ? xcd * (q + 1) : r * (q + 1) + (xcd - r) * q) + rest;
    int bx = nw / gridDim.y, by = nw - bx * gridDim.y;
    int bm = by * GBM, bn = bx * GBN;

    if (CAUSAL && bn >= bm + GBM) return;   // fully-masked tile (block-uniform exit)

    __shared__ u16 As[2][GBM * GBK];   // [buf][row*GBK + k], k contiguous
    __shared__ u16 Bs[2][GBN * GBK];

    int tid = threadIdx.x;
    int w = tid >> 6, lane = tid & 63;
    int wr = w >> 1, wc = w & 1;         // 2x2 wave grid, 64x64 per wave
    int lrow = lane & 15, kgrp = lane >> 4;

    // per-thread staging coords (chunk c -> row c/4, k-offset (c%4)*8)
    int c0row = tid >> 2, c0ko = (tid & 3) << 3;
    long ldsOff = (size_t)(w * 64) * 8;

    auto STAGE = [&](int buf, int ks) {
        int k0 = ks * GBK;
        #pragma unroll
        for (int i = 0; i < 2; i++) {
            int row = c0row + i * 64;
            int gr = bm + row; if (gr >= M) gr = M - 1;   // clamp (ragged M=8)
            const u16* srcA = A + (long)gr * lda + k0 + c0ko;
            u16* dstA = &As[buf][ldsOff + (size_t)i * 256 * 8];
            __builtin_amdgcn_global_load_lds((const __attribute__((address_space(1))) void*)srcA,
                                             (__attribute__((address_space(3))) void*)dstA, 16, 0, 0);
            const u16* srcB = B + (long)(bn + row) * ldb + k0 + c0ko;
            u16* dstB = &Bs[buf][ldsOff + (size_t)i * 256 * 8];
            __builtin_amdgcn_global_load_lds((const __attribute__((address_space(1))) void*)srcB,
                                             (__attribute__((address_space(3))) void*)dstB, 16, 0, 0);
        }
    };

    f32x4 acc[4][4] = {};
    int nsteps = K / GBK;

    STAGE(0, 0);     // 4 loads in flight

    for (int ks = 0; ks < nsteps; ks++) {
        int cur = ks & 1;
        if (ks + 1 < nsteps) {
            STAGE(cur ^ 1, ks + 1);                       // 4 more in flight (8 total)
            asm volatile("s_waitcnt vmcnt(4)" ::: "memory");   // cur's 4 done; next's fly
        } else {
            asm volatile("s_waitcnt vmcnt(0)" ::: "memory");   // final: drain
        }
        __builtin_amdgcn_s_barrier();                     // all waves' cur quarters visible
        bf16x8 av[4], bv[4];
        #pragma unroll
        for (int m = 0; m < 4; m++)
            av[m] = *(const bf16x8*)&As[cur][(wr * 64 + m * 16 + lrow) * GBK + kgrp * 8];
        #pragma unroll
        for (int n = 0; n < 4; n++)
            bv[n] = *(const bf16x8*)&Bs[cur][(wc * 64 + n * 16 + lrow) * GBK + kgrp * 8];
        #pragma unroll
        for (int m = 0; m < 4; m++)
            #pragma unroll
            for (int n = 0; n < 4; n++)
                acc[m][n] = __builtin_amdgcn_mfma_f32_16x16x32_bf16(av[m], bv[n], acc[m][n], 0, 0, 0);
        __builtin_amdgcn_s_barrier();                     // reads of cur done -> safe to overwrite
    }

    // C/D layout: col = lane&15, row = (lane>>4)*4 + reg   [m89/m91 verified]
    if (NTST) {
        __syncthreads();                  // full drain before LDS reuse
        // LDS-staged coalesced NT epilogue: 4 passes of 32 rows x 128 cols f32.
        float* ls = (float*)&As[0][0];     // 32*128 f32 = 16 KB
        C += coff;
        #pragma unroll
        for (int pass = 0; pass < 4; pass++) {
            if (wr == (pass >> 1)) {
                #pragma unroll
                for (int m2 = 0; m2 < 2; m2++) {
                    int m = (pass & 1) * 2 + m2;
                    #pragma unroll
                    for (int n = 0; n < 4; n++) {
                        int gc = wc * 64 + n * 16 + lrow;
                        float bvv = bias ? bias[bn + gc] : 0.f;
                        #pragma unroll
                        for (int r2 = 0; r2 < 4; r2++) {
                            float v2 = acc[m][n][r2] * alpha + bvv;
                            if (RELU) v2 = fmaxf(v2, 0.f);
                            ls[(m2 * 16 + kgrp * 4 + r2) * 128 + gc] = v2;
                        }
                    }
                }
            }
            __syncthreads();
            #pragma unroll
            for (int i = 0; i < 4; i++) {
                int j = tid + i * 256;            // 0..1023 f32x4
                int row = j >> 5, cg = j & 31;
                int gr = bm + pass * 32 + row;
                if (gr < M) {
                    f32x4 v4 = *(const f32x4*)&ls[row * 128 + cg * 4];
                    __builtin_nontemporal_store(v4, (f32x4*)&C[(long)gr * ldc + bn + cg * 4]);
                }
            }
            __syncthreads();
        }
        return;
    }

    if (C)  C  += coff;
    if (Cb) Cb += coff;
    #pragma unroll
    for (int m = 0; m < 4; m++) {
        int rb = bm + wr * 64 + m * 16 + kgrp * 4;
        #pragma unroll
        for (int n = 0; n < 4; n++) {
            int gc = bn + wc * 64 + n * 16 + lrow;
            float bvv = bias ? bias[gc] : 0.f;
            #pragma unroll
            for (int r2 = 0; r2 < 4; r2++) {
                int gr = rb + r2;
                if (gr < M) {
                    float v2 = acc[m][n][r2] * alpha + bvv;
                    if (RELU) v2 = fmaxf(v2, 0.f);
                    if (C)  C[(long)gr * ldc + gc]  = v2;
                    if (Cb) Cb[(long)gr * ldc + gc] = f2bf(v2);
                }
            }
        }
    }
}

// ---------------- causal softmax: f32 scores -> bf16 P ----------------
__global__ __launch_bounds__(256)
void softmax_causal_kernel(const float* __restrict__ scores, u16* __restrict__ pb)
{
    long row = blockIdx.x;                 // n*H*T + h*T + s
    int s = (int)(row % TLEN);
    const float* p = scores + row * TLEN;
    u16* o = pb + row * TLEN;
    int tid = threadIdx.x;
    float v0 = p[tid], v1 = p[tid + 256];
    bool m0 = (tid <= s), m1 = (tid + 256 <= s);
    __shared__ float red[256];
    float mx = fmaxf(m0 ? v0 : -INFINITY, m1 ? v1 : -INFINITY);
    red[tid] = mx; __syncthreads();
    for (int off = 128; off > 0; off >>= 1) {
        if (tid < off) red[tid] = fmaxf(red[tid], red[tid + off]);
        __syncthreads();
    }
    mx = red[0]; __syncthreads();
    float e0 = m0 ? expf(v0 - mx) : 0.f;
    float e1 = m1 ? expf(v1 - mx) : 0.f;
    red[tid] = e0 + e1; __syncthreads();
    for (int off = 128; off > 0; off >>= 1) {
        if (tid < off) red[tid] += red[tid + off];
        __syncthreads();
    }
    float inv = 1.f / red[0];
    o[tid]       = f2bf(e0 * inv);
    o[tid + 256] = f2bf(e1 * inv);
}

// ---------------- x = LayerNorm(x + t2); writes f32 x and bf16 xb ----------------
__global__ __launch_bounds__(256)
void add_ln_kernel(float* __restrict__ x, u16* __restrict__ xb,
                   const float* __restrict__ t2, long t2div,
                   const float* __restrict__ w, const float* __restrict__ b)
{
    long r = blockIdx.x;
    float* xr = x + r * WDIM;
    u16* xbr = xb + r * WDIM;
    const float* tr = t2 + (r / t2div) * WDIM;
    int tid = threadIdx.x;
    float v0 = xr[tid] + tr[tid];
    float v1 = xr[tid + 256] + tr[tid + 256];
    __shared__ float red[256];
    red[tid] = v0 + v1; __syncthreads();
    for (int off = 128; off > 0; off >>= 1) {
        if (tid < off) red[tid] += red[tid + off];
        __syncthreads();
    }
    float mean = red[0] * (1.f / WDIM); __syncthreads();
    float d0 = v0 - mean, d1 = v1 - mean;
    red[tid] = d0 * d0 + d1 * d1; __syncthreads();
    for (int off = 128; off > 0; off >>= 1) {
        if (tid < off) red[tid] += red[tid + off];
        __syncthreads();
    }
    float rstd = 1.f / sqrtf(red[0] * (1.f / WDIM) + 1e-5f);
    float o0 = d0 * rstd * w[tid] + b[tid];
    float o1 = d1 * rstd * w[tid + 256] + b[tid + 256];
    xr[tid] = o0;        xr[tid + 256] = o1;
    xbr[tid] = f2bf(o0); xbr[tid + 256] = f2bf(o1);
}

extern "C" void kernel_launch(void* const* d_in, const int* in_sizes, int n_in,
                              void* d_out, int out_size, void* d_ws, size_t ws_size,
                              hipStream_t stream)
{
    const float* features = (const float*)d_in[0];
    const int*   captions = (const int*)  d_in[1];
    const float* emb      = (const float*)d_in[2];
    const float* pe       = (const float*)d_in[3];
    const float* vis_w    = (const float*)d_in[4];
    const float* vis_b    = (const float*)d_in[5];
    const float* sa_wq    = (const float*)d_in[6];
    const float* sa_bq    = (const float*)d_in[7];
    const float* sa_wk    = (const float*)d_in[8];
    const float* sa_bk    = (const float*)d_in[9];
    const float* sa_wv    = (const float*)d_in[10];
    const float* sa_bv    = (const float*)d_in[11];
    const float* sa_wo    = (const float*)d_in[12];
    const float* sa_bo    = (const float*)d_in[13];
    // ca_wq/bq/wk/bk (14..17) unused: len-1 memory => softmax == 1 identically
    const float* ca_wv    = (const float*)d_in[18];
    const float* ca_bv    = (const float*)d_in[19];
    const float* ca_wo    = (const float*)d_in[20];
    const float* ca_bo    = (const float*)d_in[21];
    const float* ff1_w    = (const float*)d_in[22];
    const float* ff1_b    = (const float*)d_in[23];
    const float* ff2_w    = (const float*)d_in[24];
    const float* ff2_b    = (const float*)d_in[25];
    const float* ln1_w    = (const float*)d_in[26];
    const float* ln1_b    = (const float*)d_in[27];
    const float* ln2_w    = (const float*)d_in[28];
    const float* ln2_b    = (const float*)d_in[29];
    const float* ln3_w    = (const float*)d_in[30];
    const float* ln3_b    = (const float*)d_in[31];
    const float* out_w    = (const float*)d_in[32];
    const float* out_b    = (const float*)d_in[33];

    // ---- workspace carve ----
    char* p = (char*)d_ws;
    auto alloc = [&](size_t bytes) { char* r = p; p += (bytes + 255) & ~(size_t)255; return r; };
    float* x    = (float*)alloc((size_t)NT * WDIM * 4);
    float* t2   = (float*)alloc((size_t)NT * WDIM * 4);
    float* memb = (float*)alloc((size_t)NBATCH * WDIM * 4);
    float* cav  = (float*)alloc((size_t)NLAY * NBATCH * WDIM * 4);
    // union region: scores f32 (SA phase) | yb bf16 (PV->Oproj) | hb bf16 (FFN)
    char*  reg1 = alloc((size_t)NBATCH * NHEADS * TLEN * TLEN * 4);
    float* scores = (float*)reg1;
    u16*   yb     = (u16*)reg1;
    u16*   hb     = (u16*)reg1;
    u16* xb    = (u16*)alloc((size_t)NT * WDIM * 2);
    u16* qkvb  = (u16*)alloc((size_t)NT * QKVW * 2);
    u16* vtb   = (u16*)alloc((size_t)NT * WDIM * 2);
    u16* pb    = (u16*)alloc((size_t)NBATCH * NHEADS * TLEN * TLEN * 2);
    u16* featb = (u16*)alloc((size_t)NBATCH * DFEAT * 2);
    u16* membf = (u16*)alloc((size_t)NBATCH * WDIM * 2);
    u16* cvb   = (u16*)alloc((size_t)NLAY * NBATCH * WDIM * 2);
    float* qkv_bias = (float*)alloc((size_t)NLAY * QKVW * 4);
    u16* vis_wT = (u16*)alloc((size_t)WDIM * DFEAT * 2);
    u16* qkvT   = (u16*)alloc((size_t)NLAY * QKVW * WDIM * 2);
    u16* sa_woT = (u16*)alloc((size_t)NLAY * WDIM * WDIM * 2);
    u16* ca_wvT = (u16*)alloc((size_t)NLAY * WDIM * WDIM * 2);
    u16* ca_woT = (u16*)alloc((size_t)NLAY * WDIM * WDIM * 2);
    u16* ff1T   = (u16*)alloc((size_t)NLAY * WDIM * FFDIM * 2);
    u16* ff2T   = (u16*)alloc((size_t)NLAY * FFDIM * WDIM * 2);
    u16* out_wT = (u16*)alloc((size_t)WDIM * VOCAB * 2);

    auto gemm = [&](const u16* A, int lda, long sAn, long sAh,
                    const u16* B, int ldb, long sBn, long sBh,
                    float* C, u16* Cb, int ldc, long sCn, long sCh,
                    const float* bias, long sbias, int M, int N, int K, int HH, int batch,
                    float alpha, int mode)   // 0=plain 1=relu 2=nt 3=causal
    {
        dim3 g(N / GBN, (M + GBM - 1) / GBM, batch), blk(256);
        if (mode == 2)
            mfma_gemm_kernel<0, 1, 0><<<g, blk, 0, stream>>>(A, lda, sAn, sAh, B, ldb, sBn, sBh,
                                                             C, Cb, ldc, sCn, sCh, bias, sbias, M, N, K, HH, alpha);
        else if (mode == 1)
            mfma_gemm_kernel<1, 0, 0><<<g, blk, 0, stream>>>(A, lda, sAn, sAh, B, ldb, sBn, sBh,
                                                             C, Cb, ldc, sCn, sCh, bias, sbias, M, N, K, HH, alpha);
        else if (mode == 3)
            mfma_gemm_kernel<0, 0, 1><<<g, blk, 0, stream>>>(A, lda, sAn, sAh, B, ldb, sBn, sBh,
                                                             C, Cb, ldc, sCn, sCh, bias, sbias, M, N, K, HH, alpha);
        else
            mfma_gemm_kernel<0, 0, 0><<<g, blk, 0, stream>>>(A, lda, sAn, sAh, B, ldb, sBn, sBh,
                                                             C, Cb, ldc, sCn, sCh, bias, sbias, M, N, K, HH, alpha);
    };
    auto transposeF = [&](const float* src, int lds_, long ssn, long ssh,
                          u16* dst, int ldd, long dsn, long dsh,
                          int K, int N, int batch, int HH)
    {
        dim3 g(N / 32, K / 32, batch), blk(256);
        transpose_cvt_kernel<float><<<g, blk, 0, stream>>>(src, lds_, ssn, ssh, dst, ldd, dsn, dsh, HH);
    };
    auto transposeB = [&](const u16* src, int lds_, long ssn, long ssh,
                          u16* dst, int ldd, long dsn, long dsh,
                          int K, int N, int batch, int HH)
    {
        dim3 g(N / 32, K / 32, batch), blk(256);
        transpose_cvt_kernel<u16><<<g, blk, 0, stream>>>(src, lds_, ssn, ssh, dst, ldd, dsn, dsh, HH);
    };

    // ---- weight conversion (per call; deterministic) ----
    cvt_kernel<<<(NBATCH * DFEAT + 255) / 256, 256, 0, stream>>>(features, featb, NBATCH * DFEAT);
    concat_bias_kernel<<<(NLAY * QKVW + 255) / 256, 256, 0, stream>>>(sa_bq, sa_bk, sa_bv, qkv_bias);
    transposeF(vis_w, WDIM, 0, 0, vis_wT, DFEAT, 0, 0, DFEAT, WDIM, 1, 1);
    transposeF(sa_wq, WDIM, (long)WDIM * WDIM, 0, qkvT,                WDIM, (long)QKVW * WDIM, 0, WDIM, WDIM, NLAY, 1);
    transposeF(sa_wk, WDIM, (long)WDIM * WDIM, 0, qkvT + (long)WDIM * WDIM,     WDIM, (long)QKVW * WDIM, 0, WDIM, WDIM, NLAY, 1);
    transposeF(sa_wv, WDIM, (long)WDIM * WDIM, 0, qkvT + (long)2 * WDIM * WDIM, WDIM, (long)QKVW * WDIM, 0, WDIM, WDIM, NLAY, 1);
    transposeF(sa_wo, WDIM, (long)WDIM * WDIM, 0, sa_woT, WDIM, (long)WDIM * WDIM, 0, WDIM, WDIM, NLAY, 1);
    transposeF(ca_wv, WDIM, (long)WDIM * WDIM, 0, ca_wvT, WDIM, (long)WDIM * WDIM, 0, WDIM, WDIM, NLAY, 1);
    transposeF(ca_wo, WDIM, (long)WDIM * WDIM, 0, ca_woT, WDIM, (long)WDIM * WDIM, 0, WDIM, WDIM, NLAY, 1);
    transposeF(ff1_w, FFDIM, (long)WDIM * FFDIM, 0, ff1T, WDIM, (long)FFDIM * WDIM, 0, WDIM, FFDIM, NLAY, 1);
    transposeF(ff2_w, WDIM, (long)FFDIM * WDIM, 0, ff2T, FFDIM, (long)WDIM * FFDIM, 0, FFDIM, WDIM, NLAY, 1);
    transposeF(out_w, VOCAB, 0, 0, out_wT, WDIM, 0, 0, WDIM, VOCAB, 1, 1);

    // memory = features @ vis_w + vis_b   (8 x 512), keep f32 + bf16
    gemm(featb, DFEAT, 0, 0, vis_wT, DFEAT, 0, 0, memb, membf, WDIM, 0, 0,
         vis_b, 0, NBATCH, WDIM, DFEAT, 1, 1, 1.f, 0);
    // x = emb[captions] + pe
    embed_kernel<<<NT, 128, 0, stream>>>(captions, emb, pe, x, xb);

    // ---- cross-attention, layer-batched (len-1 memory => softmax == 1) ----
    // cvb[l] = membf @ ca_wv[l] + ca_bv[l];  cav[l] = cvb[l] @ ca_wo[l] + ca_bo[l]
    gemm(membf, WDIM, 0, 0, ca_wvT, WDIM, (long)WDIM * WDIM, 0,
         nullptr, cvb, WDIM, (long)NBATCH * WDIM, 0,
         ca_bv, WDIM, NBATCH, WDIM, WDIM, 1, NLAY, 1.f, 0);
    gemm(cvb, WDIM, (long)NBATCH * WDIM, 0, ca_woT, WDIM, (long)WDIM * WDIM, 0,
         cav, nullptr, WDIM, (long)NBATCH * WDIM, 0,
         ca_bo, WDIM, NBATCH, WDIM, WDIM, 1, NLAY, 1.f, 0);

    const float iscale = 1.f / sqrtf((float)DHEAD);
    const long TQ = (long)TLEN * QKVW;
    const long TW = (long)TLEN * WDIM;
    const long TT = (long)TLEN * TLEN;
    for (int l = 0; l < NLAY; l++) {
        long wo  = (long)l * WDIM * WDIM;
        long bo_ = (long)l * WDIM;
        // ---- self-attention: fused QKV projection (N=1536) ----
        gemm(xb, WDIM, 0, 0, qkvT + (long)l * QKVW * WDIM, WDIM, 0, 0,
             nullptr, qkvb, QKVW, 0, 0, qkv_bias + (long)l * QKVW, 0,
             NT, QKVW, WDIM, 1, 1, 1.f, 0);
        // V^T per (n,h): qkvb[n*T+t][1024 + h*128 + d] -> vtb [n][h][d][t]
        transposeB(qkvb + 2 * WDIM, QKVW, TQ, DHEAD,
                   vtb, TLEN, (long)NHEADS * DHEAD * TLEN, (long)DHEAD * TLEN,
                   TLEN, DHEAD, NBATCH * NHEADS, NHEADS);
        // scores = (Q_h @ K_h^T) * iscale  (causal: skip fully-masked tiles)
        gemm(qkvb, QKVW, TQ, DHEAD, qkvb + WDIM, QKVW, TQ, DHEAD,
             scores, nullptr, TLEN, (long)NHEADS * TT, TT,
             nullptr, 0, TLEN, TLEN, DHEAD, NHEADS, NBATCH * NHEADS, iscale, 3);
        softmax_causal_kernel<<<NBATCH * NHEADS * TLEN, 256, 0, stream>>>(scores, pb);
        // y = P @ V_h  (B = V^T tile, (N=d, K=t))
        gemm(pb, TLEN, (long)NHEADS * TT, TT,
             vtb, TLEN, (long)NHEADS * DHEAD * TLEN, (long)DHEAD * TLEN,
             nullptr, yb, WDIM, TW, DHEAD,
             nullptr, 0, TLEN, DHEAD, TLEN, NHEADS, NBATCH * NHEADS, 1.f, 0);
        // t2 = y @ wo + bo
        gemm(yb, WDIM, 0, 0, sa_woT + wo, WDIM, 0, 0, t2, nullptr, WDIM, 0, 0,
             sa_bo + bo_, 0, NT, WDIM, WDIM, 1, 1, 1.f, 0);
        add_ln_kernel<<<NT, 256, 0, stream>>>(x, xb, t2, 1, ln1_w + bo_, ln1_b + bo_);
        add_ln_kernel<<<NT, 256, 0, stream>>>(x, xb, cav + (long)l * NBATCH * WDIM, TLEN,
                                              ln2_w + bo_, ln2_b + bo_);
        // ---- FFN ----
        gemm(xb, WDIM, 0, 0, ff1T + (long)l * FFDIM * WDIM, WDIM, 0, 0,
             nullptr, hb, FFDIM, 0, 0, ff1_b + (long)l * FFDIM, 0,
             NT, FFDIM, WDIM, 1, 1, 1.f, 1);
        gemm(hb, FFDIM, 0, 0, ff2T + (long)l * WDIM * FFDIM, FFDIM, 0, 0,
             t2, nullptr, WDIM, 0, 0, ff2_b + bo_, 0, NT, WDIM, FFDIM, 1, 1, 1.f, 0);
        add_ln_kernel<<<NT, 256, 0, stream>>>(x, xb, t2, 1, ln3_w + bo_, ln3_b + bo_);
    }
    // out = x @ out_w + out_b   (4096 x 32000) — coalesced non-temporal f32 stores
    gemm(xb, WDIM, 0, 0, out_wT, WDIM, 0, 0, (float*)d_out, nullptr, VOCAB, 0, 0,
         out_b, 0, NT, VOCAB, WDIM, 1, 1, 1.f, 2);
}